// Round 1
// baseline (697.831 us; speedup 1.0000x reference)
//
#include <hip/hip_runtime.h>
#include <math.h>

#define NEG9 (-1e9f)

// ---- fixed problem sizes ----
// B=4, L=1024, D=512, H=8, HD=64, HID=256, WIN=32 (half=16), KK=716, TEMP=1, scale=1/8

// ---- workspace layout (float offsets) ----
#define OFF_Q   ((size_t)0)         // q  [32][1024][64]
#define OFF_K   ((size_t)2097152)   // kT [32][64][1024]  (transposed)
#define OFF_V   ((size_t)4194304)   // v  [32][1024][64]
#define OFF_AT  ((size_t)6291456)   // attn out [4096][512]
#define OFF_PW  ((size_t)8388608)   // pw [4][3]
#define OFF_PAR ((size_t)8388864)   // pooling partials [4][16][512]
// total = 8,421,632 floats = 33.7 MB

// ============================================================
// Pooling stage 1: partial sums over l-chunks of 64
// grid (4, 16), block 256
// ============================================================
__global__ __launch_bounds__(256)
void pool_stage1(const float* __restrict__ x, float* __restrict__ partial)
{
    const int b = blockIdx.x, lb = blockIdx.y, t = threadIdx.x;
    const float* xb = x + ((size_t)b * 1024 + lb * 64) * 512;
    float s0 = 0.f, s1 = 0.f;
    for (int l = 0; l < 64; ++l) {
        s0 += xb[l * 512 + t];
        s1 += xb[l * 512 + t + 256];
    }
    partial[((size_t)b * 16 + lb) * 512 + t] = s0;
    partial[((size_t)b * 16 + lb) * 512 + t + 256] = s1;
}

// ============================================================
// Selector: pooled -> relu(W1 pooled + b1) -> W2 -> softmax(/tau) -> pw
// grid 4, block 256
// ============================================================
__global__ __launch_bounds__(256)
void selector_kernel(const float* __restrict__ partial,
                     const float* __restrict__ W1, const float* __restrict__ b1,
                     const float* __restrict__ W2, const float* __restrict__ b2,
                     const float* __restrict__ ltau, float* __restrict__ pwout)
{
    __shared__ float pooled[512];
    __shared__ float h1[256];
    __shared__ float lg[3];
    const int b = blockIdx.x, t = threadIdx.x;
    float s0 = 0.f, s1 = 0.f;
    for (int p = 0; p < 16; ++p) {
        s0 += partial[((size_t)b * 16 + p) * 512 + t];
        s1 += partial[((size_t)b * 16 + p) * 512 + t + 256];
    }
    pooled[t]       = s0 * (1.f / 1024.f);
    pooled[t + 256] = s1 * (1.f / 1024.f);
    __syncthreads();
    float acc = b1[t];
    const float* w1 = W1 + (size_t)t * 512;
    for (int d = 0; d < 512; d += 4) {
        float4 w4 = *(const float4*)(w1 + d);
        acc += w4.x * pooled[d] + w4.y * pooled[d + 1] + w4.z * pooled[d + 2] + w4.w * pooled[d + 3];
    }
    h1[t] = fmaxf(acc, 0.f);
    __syncthreads();
    if (t < 3) {
        float a = b2[t];
        const float* w2 = W2 + t * 256;
        for (int i = 0; i < 256; ++i) a += w2[i] * h1[i];
        float tauv = fminf(fmaxf(expf(ltau[0]), 1e-4f), 10.f);
        lg[t] = a / tauv;
    }
    __syncthreads();
    if (t == 0) {
        float m = fmaxf(lg[0], fmaxf(lg[1], lg[2]));
        float e0 = expf(lg[0] - m), e1 = expf(lg[1] - m), e2 = expf(lg[2] - m);
        float inv = 1.f / (e0 + e1 + e2);
        pwout[b * 3 + 0] = e0 * inv;
        pwout[b * 3 + 1] = e1 * inv;
        pwout[b * 3 + 2] = e2 * inv;
    }
}

// ============================================================
// fp32 GEMM: out[m][n] = sum_k A[m][k] * W[n][k]   (A MxK row-major, W NxK row-major)
// 64x64 block tile, 4x4 micro, BK=16, K=512 fixed.
// mode 0: QKV scatter (q natural / kT transposed / v natural)
// mode 1: plain + bias
// ============================================================
__global__ __launch_bounds__(256)
void gemm64(const float* __restrict__ A, const float* __restrict__ W,
            const float* __restrict__ bias,
            float* __restrict__ dq, float* __restrict__ dk, float* __restrict__ dv,
            float* __restrict__ dout, const int mode)
{
    __shared__ float As[16][68];
    __shared__ float Ws[16][68];
    const int t = threadIdx.x;
    const int tx = t & 15, ty = t >> 4;
    const int m0 = blockIdx.y << 6, n0 = blockIdx.x << 6;
    const int mm = t >> 2, kq = t & 3;
    float acc[4][4] = {};
    const float* Ap = A + (size_t)(m0 + mm) * 512 + kq * 4;
    const float* Wp = W + (size_t)(n0 + mm) * 512 + kq * 4;
    for (int kc = 0; kc < 32; ++kc) {
        float4 a4 = *(const float4*)(Ap + kc * 16);
        float4 w4 = *(const float4*)(Wp + kc * 16);
        __syncthreads();
        As[kq * 4 + 0][mm] = a4.x; As[kq * 4 + 1][mm] = a4.y;
        As[kq * 4 + 2][mm] = a4.z; As[kq * 4 + 3][mm] = a4.w;
        Ws[kq * 4 + 0][mm] = w4.x; Ws[kq * 4 + 1][mm] = w4.y;
        Ws[kq * 4 + 2][mm] = w4.z; Ws[kq * 4 + 3][mm] = w4.w;
        __syncthreads();
        #pragma unroll
        for (int k = 0; k < 16; ++k) {
            float4 av = *(const float4*)&As[k][tx * 4];
            float4 wv = *(const float4*)&Ws[k][ty * 4];
            acc[0][0] += av.x * wv.x; acc[0][1] += av.x * wv.y; acc[0][2] += av.x * wv.z; acc[0][3] += av.x * wv.w;
            acc[1][0] += av.y * wv.x; acc[1][1] += av.y * wv.y; acc[1][2] += av.y * wv.z; acc[1][3] += av.y * wv.w;
            acc[2][0] += av.z * wv.x; acc[2][1] += av.z * wv.y; acc[2][2] += av.z * wv.z; acc[2][3] += av.z * wv.w;
            acc[3][0] += av.w * wv.x; acc[3][1] += av.w * wv.y; acc[3][2] += av.w * wv.z; acc[3][3] += av.w * wv.w;
        }
    }
    if (mode == 0) {
        const int which = n0 >> 9;          // 0=q 1=k 2=v (block spans one which/h)
        const int hh = (n0 >> 6) & 7;
        #pragma unroll
        for (int i = 0; i < 4; ++i) {
            int m = m0 + tx * 4 + i;
            int bb = m >> 10, ll = m & 1023;
            int gg = bb * 8 + hh;
            if (which == 1) {
                #pragma unroll
                for (int j = 0; j < 4; ++j)
                    dk[((size_t)gg * 64 + ty * 4 + j) * 1024 + ll] = acc[i][j];
            } else {
                float* dst = (which == 0 ? dq : dv) + ((size_t)gg * 1024 + ll) * 64 + ty * 4;
                float4 o; o.x = acc[i][0]; o.y = acc[i][1]; o.z = acc[i][2]; o.w = acc[i][3];
                *(float4*)dst = o;
            }
        }
    } else {
        float4 bv = *(const float4*)(bias + n0 + ty * 4);
        #pragma unroll
        for (int i = 0; i < 4; ++i) {
            int m = m0 + tx * 4 + i;
            float4 o;
            o.x = acc[i][0] + bv.x; o.y = acc[i][1] + bv.y;
            o.z = acc[i][2] + bv.z; o.w = acc[i][3] + bv.w;
            *(float4*)&dout[(size_t)m * 512 + n0 + ty * 4] = o;
        }
    }
}

// ============================================================
// Fused streaming attention.
// grid 2048 (g = bid&31 -> (b,h) keeps same (b,h) on same XCD; tile = bid>>5),
// block 256 (4 waves). 16 query rows per block, 8 chunks of 128 keys.
// Online softmax; exact reference semantics for mask/local/sparse/fallback.
// ============================================================
__global__ __launch_bounds__(256)
void attn_kernel(const float* __restrict__ q, const float* __restrict__ kT,
                 const float* __restrict__ v, const int* __restrict__ mask,
                 const float* __restrict__ pw, const float* __restrict__ sw,
                 const float* __restrict__ sb, float* __restrict__ aout)
{
    __shared__ float qT[64 * 16];          // qT[e][r], scale folded in
    __shared__ float Sc[16 * 132];         // score/P chunk [r][j'] (pad 132)
    __shared__ float kv[8704];             // union: ktc [64][132] / vtc [128][68]
    __shared__ int   mk[1024];
    __shared__ float mrow[16], lrow[16], arow[16];
    __shared__ unsigned kthu[16];

    const int t = threadIdx.x;
    const int g = blockIdx.x & 31;
    const int tile = blockIdx.x >> 5;
    const int b = g >> 3, h = g & 7;
    const int i0 = tile << 4;
    const int lane = t & 63, wvid = t >> 6;

    const float* qg = q + ((size_t)g * 1024 + i0) * 64;
    const float* kg = kT + (size_t)g * 64 * 1024;
    const float* vg = v + (size_t)g * 1024 * 64;

    {   // Q tile -> qT[e][r], fold scale=0.125 (exact, pow2)
        int r = t & 15, e4 = t >> 4;
        float4 q4 = *(const float4*)(qg + (size_t)r * 64 + e4 * 4);
        qT[(e4 * 4 + 0) * 16 + r] = q4.x * 0.125f;
        qT[(e4 * 4 + 1) * 16 + r] = q4.y * 0.125f;
        qT[(e4 * 4 + 2) * 16 + r] = q4.z * 0.125f;
        qT[(e4 * 4 + 3) * 16 + r] = q4.w * 0.125f;
    }
    {
        int4 m4 = *(const int4*)(mask + b * 1024 + t * 4);
        mk[t * 4 + 0] = m4.x; mk[t * 4 + 1] = m4.y;
        mk[t * 4 + 2] = m4.z; mk[t * 4 + 3] = m4.w;
    }
    if (t < 16) { mrow[t] = -3e38f; lrow[t] = 0.f; arow[t] = 0.f; }

    // combined-mask booleans (match reference float op order exactly)
    const float pw0 = pw[b * 3 + 0], pw1 = pw[b * 3 + 1], pw2 = pw[b * 3 + 2];
    const bool a00 = pw1 > 0.05f;
    const bool a10 = (pw0 * 1.0f + pw1) > 0.05f;
    const bool a01 = (pw1 + pw2) > 0.05f;
    const bool a11 = ((pw0 * 1.0f + pw1) + pw2) > 0.05f;
    const bool need_sparse = (!a00 && a01) || (!a10 && a11);
    const float w_h = sw[h], b_h = sb[h];
    __syncthreads();

    // ---- rare path: exact kth-largest (k=716) per row via bitwise radix select ----
    if (need_sparse) {
        unsigned* ubuf = (unsigned*)kv;
        for (int r = 0; r < 16; ++r) {
            float s0 = 0.f, s1 = 0.f, s2 = 0.f, s3 = 0.f;
            for (int e = 0; e < 64; ++e) {
                float qe = qT[e * 16 + r];
                float4 k4 = *(const float4*)(kg + (size_t)e * 1024 + t * 4);
                s0 += qe * k4.x; s1 += qe * k4.y; s2 += qe * k4.z; s3 += qe * k4.w;
            }
            float sv[4] = { s0, s1, s2, s3 };
            #pragma unroll
            for (int c = 0; c < 4; ++c) {
                unsigned ub = __float_as_uint(sv[c] * w_h + b_h);
                ubuf[t * 4 + c] = (ub & 0x80000000u) ? ~ub : (ub | 0x80000000u);
            }
            __syncthreads();
            if (wvid == 0) {
                unsigned u[16];
                #pragma unroll
                for (int qq = 0; qq < 16; ++qq) u[qq] = ubuf[lane + qq * 64];
                unsigned act = 0xFFFFu, p = 0u;
                int k = 716;
                for (int bit = 31; bit >= 0; --bit) {
                    unsigned ones = 0u;
                    #pragma unroll
                    for (int qq = 0; qq < 16; ++qq)
                        if (((act >> qq) & 1u) && ((u[qq] >> bit) & 1u)) ones |= (1u << qq);
                    int c1 = __popc(ones);
                    for (int off = 32; off; off >>= 1) c1 += __shfl_xor(c1, off);
                    if (k <= c1) { p |= (1u << bit); act &= ones; }
                    else         { k -= c1; act &= ~ones; }
                }
                if (lane == 0) kthu[r] = p;
            }
            __syncthreads();
        }
    }

    // ---- streaming attention ----
    float acc0 = 0.f, acc1 = 0.f, acc2 = 0.f, acc3 = 0.f;
    const int tr = t >> 4;             // PV row 0..15
    const int te = (t & 15) * 4;       // PV e-quad
    const int jl = t & 127, rh = t >> 7;

    for (int jc = 0; jc < 8; ++jc) {
        const int j0 = jc << 7;
        __syncthreads();
        // stage K chunk: ktc[e][j'] (kT layout -> coalesced b128, conflict-free LDS)
        #pragma unroll
        for (int it = 0; it < 8; ++it) {
            int idx = it * 256 + t;
            int e = idx >> 5, j4 = idx & 31;
            float4 k4 = *(const float4*)(kg + (size_t)e * 1024 + j0 + j4 * 4);
            *(float4*)&kv[e * 132 + j4 * 4] = k4;
        }
        __syncthreads();
        // score chunk: rows rh*8..+7, col jl  (q broadcast from LDS, 8 FMA / k-read)
        {
            float a8[8] = { 0, 0, 0, 0, 0, 0, 0, 0 };
            for (int e = 0; e < 64; ++e) {
                float kk = kv[e * 132 + jl];
                float4 qa = *(const float4*)&qT[e * 16 + rh * 8];
                float4 qb = *(const float4*)&qT[e * 16 + rh * 8 + 4];
                a8[0] += qa.x * kk; a8[1] += qa.y * kk; a8[2] += qa.z * kk; a8[3] += qa.w * kk;
                a8[4] += qb.x * kk; a8[5] += qb.y * kk; a8[6] += qb.z * kk; a8[7] += qb.w * kk;
            }
            #pragma unroll
            for (int rr = 0; rr < 8; ++rr) Sc[(rh * 8 + rr) * 132 + jl] = a8[rr];
        }
        __syncthreads();
        // stage V chunk (overwrites ktc) while doing the online-softmax update
        #pragma unroll
        for (int it = 0; it < 8; ++it) {
            int idx = it * 256 + t;
            int eq = idx & 15, j = idx >> 4;
            float4 v4 = *(const float4*)(vg + (size_t)(j0 + j) * 64 + eq * 4);
            *(float4*)&kv[j * 68 + eq * 4] = v4;
        }
        for (int rr = 0; rr < 4; ++rr) {
            int r = wvid * 4 + rr;
            int ia = i0 + r;
            float se0, se1;
            #pragma unroll
            for (int xx = 0; xx < 2; ++xx) {
                int jj = lane + xx * 64;
                int ja = j0 + jj;
                float s = Sc[r * 132 + jj];
                bool loc = (ja >= ia - 16) && (ja <= ia + 16);
                bool sm = false;
                if (need_sparse) {
                    unsigned ub = __float_as_uint(s * w_h + b_h);
                    unsigned key = (ub & 0x80000000u) ? ~ub : (ub | 0x80000000u);
                    sm = (key >= kthu[r]);
                }
                bool allowed = loc ? (sm ? a11 : a10) : (sm ? a01 : a00);
                if (mk[ja] == 0) allowed = false;
                float se = allowed ? s : NEG9;
                if (xx == 0) se0 = se; else se1 = se;
            }
            float cm = fmaxf(se0, se1);
            for (int off = 32; off; off >>= 1) cm = fmaxf(cm, __shfl_xor(cm, off));
            float mo = mrow[r];
            float mn = fmaxf(mo, cm);
            float p0 = __expf(se0 - mn), p1 = __expf(se1 - mn);
            Sc[r * 132 + lane] = p0;
            Sc[r * 132 + lane + 64] = p1;
            float cs = p0 + p1;
            for (int off = 32; off; off >>= 1) cs += __shfl_xor(cs, off);
            if (lane == 0) {
                float al = __expf(mo - mn);
                arow[r] = al;
                lrow[r] = lrow[r] * al + cs;
                mrow[r] = mn;
            }
        }
        __syncthreads();
        // PV accumulate (registers), rescale by alpha
        {
            float al = arow[tr];
            acc0 *= al; acc1 *= al; acc2 *= al; acc3 *= al;
            for (int jj = 0; jj < 128; jj += 4) {
                float4 p4 = *(const float4*)&Sc[tr * 132 + jj];
                float4 v0 = *(const float4*)&kv[(jj + 0) * 68 + te];
                float4 v1 = *(const float4*)&kv[(jj + 1) * 68 + te];
                float4 v2 = *(const float4*)&kv[(jj + 2) * 68 + te];
                float4 v3 = *(const float4*)&kv[(jj + 3) * 68 + te];
                acc0 += p4.x * v0.x + p4.y * v1.x + p4.z * v2.x + p4.w * v3.x;
                acc1 += p4.x * v0.y + p4.y * v1.y + p4.z * v2.y + p4.w * v3.y;
                acc2 += p4.x * v0.z + p4.y * v1.z + p4.z * v2.z + p4.w * v3.z;
                acc3 += p4.x * v0.w + p4.y * v1.w + p4.z * v2.w + p4.w * v3.w;
            }
        }
    }

    float mfin = mrow[tr], lfin = lrow[tr];
    float4 o;
    if (mfin <= NEG9 + 1e-6f) {
        // fully-masked row: reference unmasks position 0 -> softmax is exact one-hot -> out = v[0]
        o = *(const float4*)(vg + te);
    } else {
        float inv = 1.f / lfin;
        o.x = acc0 * inv; o.y = acc1 * inv; o.z = acc2 * inv; o.w = acc3 * inv;
    }
    *(float4*)&aout[((size_t)(b * 1024 + i0 + tr)) * 512 + h * 64 + te] = o;
}

// ============================================================
extern "C" void kernel_launch(void* const* d_in, const int* in_sizes, int n_in,
                              void* d_out, int out_size, void* d_ws, size_t ws_size,
                              hipStream_t stream) {
    const float* x     = (const float*)d_in[0];
    const int*   mask  = (const int*)d_in[1];
    const float* Wqkv  = (const float*)d_in[2];
    const float* Wproj = (const float*)d_in[3];
    const float* bproj = (const float*)d_in[4];
    const float* Wsel1 = (const float*)d_in[5];
    const float* bsel1 = (const float*)d_in[6];
    const float* Wsel2 = (const float*)d_in[7];
    const float* bsel2 = (const float*)d_in[8];
    const float* ltau  = (const float*)d_in[9];
    const float* sw    = (const float*)d_in[10];
    const float* sb    = (const float*)d_in[11];
    float* ws   = (float*)d_ws;
    float* q    = ws + OFF_Q;
    float* kT   = ws + OFF_K;
    float* v    = ws + OFF_V;
    float* attn = ws + OFF_AT;
    float* pw   = ws + OFF_PW;
    float* par  = ws + OFF_PAR;
    float* out  = (float*)d_out;
    (void)in_sizes; (void)n_in; (void)out_size; (void)ws_size;

    pool_stage1<<<dim3(4, 16), 256, 0, stream>>>(x, par);
    selector_kernel<<<4, 256, 0, stream>>>(par, Wsel1, bsel1, Wsel2, bsel2, ltau, pw);
    gemm64<<<dim3(24, 64), 256, 0, stream>>>(x, Wqkv, nullptr, q, kT, v, nullptr, 0);
    attn_kernel<<<2048, 256, 0, stream>>>(q, kT, v, mask, pw, sw, sb, attn);
    gemm64<<<dim3(8, 64), 256, 0, stream>>>(attn, Wproj, bproj, nullptr, nullptr, nullptr, out, 1);
}

// Round 2
// 250.945 us; speedup vs baseline: 2.7808x; 2.7808x over previous
//
#include <hip/hip_runtime.h>
#include <math.h>

typedef __attribute__((ext_vector_type(8))) short short8;
typedef __attribute__((ext_vector_type(4))) float floatx4;

#define MFMA16(a, b, c) __builtin_amdgcn_mfma_f32_16x16x32_bf16(a, b, c, 0, 0, 0)

// ---- fixed sizes: B=4 L=1024 D=512 H=8 HD=64 HID=256 half-win=16 KK=716 scale=1/8 ----

// ---- workspace byte offsets ----
#define OFF_XB    ((size_t)0)          // x bf16 [4096][512]
#define OFF_WQKV  ((size_t)4194304)    // Wqkv bf16 [1536][512]
#define OFF_WPROJ ((size_t)5767168)    // Wproj bf16 [512][512]
#define OFF_Q     ((size_t)6291456)    // q bf16 [32][1024][64] (scale folded)
#define OFF_K     ((size_t)10485760)   // k bf16 [32][1024][64]
#define OFF_VT    ((size_t)14680064)   // vT bf16 [32][64][1024]
#define OFF_AT    ((size_t)18874368)   // attn out bf16 [4096][512]
#define OFF_PW    ((size_t)23068672)   // pw fp32 [4][3]
#define OFF_PAR   ((size_t)23068928)   // pool partials fp32 [4][16][512]
// total ~23.2 MB (round-1 used 33.7 MB OK)

__device__ __forceinline__ unsigned short f2bf(float f) {  // RNE
    unsigned u = __float_as_uint(f);
    return (unsigned short)((u + 0x7fffu + ((u >> 16) & 1u)) >> 16);
}
__device__ __forceinline__ float bf2f(unsigned short s) {
    return __uint_as_float((unsigned)s << 16);
}

// ============================================================
__global__ __launch_bounds__(256)
void cvt_bf16(const float* __restrict__ in, unsigned short* __restrict__ out, int n4)
{
    int i = blockIdx.x * 256 + threadIdx.x;
    if (i < n4) {
        float4 f = ((const float4*)in)[i];
        ushort4 o = make_ushort4(f2bf(f.x), f2bf(f.y), f2bf(f.z), f2bf(f.w));
        ((ushort4*)out)[i] = o;
    }
}

// ============================================================
__global__ __launch_bounds__(256)
void pool_stage1(const float* __restrict__ x, float* __restrict__ partial)
{
    const int b = blockIdx.x, lb = blockIdx.y, t = threadIdx.x;
    const float* xb = x + ((size_t)b * 1024 + lb * 64) * 512;
    float s0 = 0.f, s1 = 0.f;
    for (int l = 0; l < 64; ++l) {
        s0 += xb[l * 512 + t];
        s1 += xb[l * 512 + t + 256];
    }
    partial[((size_t)b * 16 + lb) * 512 + t] = s0;
    partial[((size_t)b * 16 + lb) * 512 + t + 256] = s1;
}

// ============================================================
__global__ __launch_bounds__(256)
void selector_kernel(const float* __restrict__ partial,
                     const float* __restrict__ W1, const float* __restrict__ b1,
                     const float* __restrict__ W2, const float* __restrict__ b2,
                     const float* __restrict__ ltau, float* __restrict__ pwout)
{
    __shared__ float pooled[512];
    __shared__ float h1[256];
    __shared__ float lg[3];
    const int b = blockIdx.x, t = threadIdx.x;
    float s0 = 0.f, s1 = 0.f;
    for (int p = 0; p < 16; ++p) {
        s0 += partial[((size_t)b * 16 + p) * 512 + t];
        s1 += partial[((size_t)b * 16 + p) * 512 + t + 256];
    }
    pooled[t]       = s0 * (1.f / 1024.f);
    pooled[t + 256] = s1 * (1.f / 1024.f);
    __syncthreads();
    float acc = b1[t];
    const float* w1 = W1 + (size_t)t * 512;
    for (int d = 0; d < 512; d += 4) {
        float4 w4 = *(const float4*)(w1 + d);
        acc += w4.x * pooled[d] + w4.y * pooled[d + 1] + w4.z * pooled[d + 2] + w4.w * pooled[d + 3];
    }
    h1[t] = fmaxf(acc, 0.f);
    __syncthreads();
    if (t < 3) {
        float a = b2[t];
        const float* w2 = W2 + t * 256;
        for (int i = 0; i < 256; ++i) a += w2[i] * h1[i];
        float tauv = fminf(fmaxf(expf(ltau[0]), 1e-4f), 10.f);
        lg[t] = a / tauv;
    }
    __syncthreads();
    if (t == 0) {
        float m = fmaxf(lg[0], fmaxf(lg[1], lg[2]));
        float e0 = expf(lg[0] - m), e1 = expf(lg[1] - m), e2 = expf(lg[2] - m);
        float inv = 1.f / (e0 + e1 + e2);
        pwout[b * 3 + 0] = e0 * inv;
        pwout[b * 3 + 1] = e1 * inv;
        pwout[b * 3 + 2] = e2 * inv;
    }
}

// ============================================================
// QKV GEMM, bf16 MFMA, direct-from-global fragments (all data L2-resident).
// block 256 = 4 waves, each wave 64x64 out. grid (12, 32): N=1536, M=4096, K=512.
// Epilogue scatters to q (scale 1/8 folded), k (natural [l][e]), vT ([e][l]).
// ============================================================
__global__ __launch_bounds__(256)
void gemm_qkv(const unsigned short* __restrict__ xb, const unsigned short* __restrict__ wb,
              unsigned short* __restrict__ qo, unsigned short* __restrict__ ko,
              unsigned short* __restrict__ vTo)
{
    const int t = threadIdx.x;
    const int w = t >> 6, l64 = t & 63;
    const int ln = l64 & 15, quad = l64 >> 4;
    const int m0 = blockIdx.y * 128 + (w & 1) * 64;
    const int n0 = blockIdx.x * 128 + (w >> 1) * 64;
    floatx4 acc[4][4];
    #pragma unroll
    for (int i = 0; i < 4; ++i)
        #pragma unroll
        for (int j = 0; j < 4; ++j) acc[i][j] = (floatx4){0.f, 0.f, 0.f, 0.f};

    for (int ks = 0; ks < 16; ++ks) {
        short8 a[4], bf[4];
        #pragma unroll
        for (int i = 0; i < 4; ++i)
            a[i] = *(const short8*)(xb + (size_t)(m0 + i * 16 + ln) * 512 + ks * 32 + quad * 8);
        #pragma unroll
        for (int j = 0; j < 4; ++j)
            bf[j] = *(const short8*)(wb + (size_t)(n0 + j * 16 + ln) * 512 + ks * 32 + quad * 8);
        #pragma unroll
        for (int i = 0; i < 4; ++i)
            #pragma unroll
            for (int j = 0; j < 4; ++j)
                acc[i][j] = MFMA16(a[i], bf[j], acc[i][j]);
    }
    // C layout: col = ln, row = quad*4 + reg
    #pragma unroll
    for (int j = 0; j < 4; ++j) {
        const int colb = n0 + j * 16;
        const int which = colb >> 9;
        const int hh = (colb >> 6) & 7;
        const int e = (colb & 63) + ln;
        #pragma unroll
        for (int i = 0; i < 4; ++i)
            #pragma unroll
            for (int reg = 0; reg < 4; ++reg) {
                const int row = m0 + i * 16 + quad * 4 + reg;
                const int bb = row >> 10, ll = row & 1023;
                const int gg = bb * 8 + hh;
                const float vvv = acc[i][j][reg];
                if (which == 0)      qo[((size_t)gg * 1024 + ll) * 64 + e] = f2bf(vvv * 0.125f);
                else if (which == 1) ko[((size_t)gg * 1024 + ll) * 64 + e] = f2bf(vvv);
                else                 vTo[((size_t)gg * 64 + e) * 1024 + ll] = f2bf(vvv);
            }
    }
}

// ============================================================
// Proj GEMM: attn(bf16) @ Wproj^T + bias -> fp32 out. grid (4, 32).
// ============================================================
__global__ __launch_bounds__(256)
void gemm_proj(const unsigned short* __restrict__ ab, const unsigned short* __restrict__ wb,
               const float* __restrict__ bias, float* __restrict__ out)
{
    const int t = threadIdx.x;
    const int w = t >> 6, l64 = t & 63;
    const int ln = l64 & 15, quad = l64 >> 4;
    const int m0 = blockIdx.y * 128 + (w & 1) * 64;
    const int n0 = blockIdx.x * 128 + (w >> 1) * 64;
    floatx4 acc[4][4];
    #pragma unroll
    for (int i = 0; i < 4; ++i)
        #pragma unroll
        for (int j = 0; j < 4; ++j) acc[i][j] = (floatx4){0.f, 0.f, 0.f, 0.f};

    for (int ks = 0; ks < 16; ++ks) {
        short8 a[4], bf[4];
        #pragma unroll
        for (int i = 0; i < 4; ++i)
            a[i] = *(const short8*)(ab + (size_t)(m0 + i * 16 + ln) * 512 + ks * 32 + quad * 8);
        #pragma unroll
        for (int j = 0; j < 4; ++j)
            bf[j] = *(const short8*)(wb + (size_t)(n0 + j * 16 + ln) * 512 + ks * 32 + quad * 8);
        #pragma unroll
        for (int i = 0; i < 4; ++i)
            #pragma unroll
            for (int j = 0; j < 4; ++j)
                acc[i][j] = MFMA16(a[i], bf[j], acc[i][j]);
    }
    #pragma unroll
    for (int j = 0; j < 4; ++j) {
        const int colb = n0 + j * 16;
        const float bv = bias[colb + ln];
        #pragma unroll
        for (int i = 0; i < 4; ++i)
            #pragma unroll
            for (int reg = 0; reg < 4; ++reg) {
                const int row = m0 + i * 16 + quad * 4 + reg;
                out[(size_t)row * 512 + colb + ln] = acc[i][j][reg] + bv;
            }
    }
}

// ============================================================
// Fused attention, bf16 MFMA, zero barriers in the main loop.
// grid 512 = 32 (b,h) groups x 16 row-tiles of 64; block 256 = 4 waves x 16 rows.
// QK^T: A = q rows (direct global), B = k rows (direct global), K=64 -> 2 MFMAs/tile.
// Online softmax fully in registers (C-layout rows = quad*4+reg; width-16 shuffles).
// P: C-layout -> LDS (wave-private, bf16, ld=144 for alignment+banks) -> A-layout.
// PV: B = vT rows (direct global), K=128 -> 4 k-steps.
// ============================================================
__global__ __launch_bounds__(256)
void attn_mfma(const unsigned short* __restrict__ qm, const unsigned short* __restrict__ km,
               const unsigned short* __restrict__ vT, const int* __restrict__ mask,
               const float* __restrict__ pw, const float* __restrict__ sw,
               const float* __restrict__ sb, unsigned short* __restrict__ aout)
{
    __shared__ int mk[1024];
    __shared__ unsigned short Pl[4][16 * 144];
    __shared__ unsigned kth_l[4][16];

    const int t = threadIdx.x;
    const int w = t >> 6, l64 = t & 63;
    const int ln = l64 & 15, quad = l64 >> 4;
    const int g = blockIdx.x & 31;           // (b,h): same group adjacent -> XCD/L2 locality
    const int rt = blockIdx.x >> 5;
    const int b = g >> 3, h = g & 7;
    const int i0 = rt * 64 + w * 16;         // this wave's first query row

    const unsigned short* qg = qm + (size_t)g * 1024 * 64;
    const unsigned short* kg = km + (size_t)g * 1024 * 64;
    const unsigned short* vg = vT + (size_t)g * 64 * 1024;

    *(int4*)&mk[t * 4] = *(const int4*)(mask + b * 1024 + t * 4);

    const float pw0 = pw[b * 3 + 0], pw1 = pw[b * 3 + 1], pw2 = pw[b * 3 + 2];
    const bool a00 = pw1 > 0.05f;
    const bool a10 = (pw0 * 1.0f + pw1) > 0.05f;
    const bool a01 = (pw1 + pw2) > 0.05f;
    const bool a11 = ((pw0 * 1.0f + pw1) + pw2) > 0.05f;
    const bool need_sparse = (!a00 && a01) || (!a10 && a11);
    const float w_h = sw[h], b_h = sb[h];
    __syncthreads();   // mask ready; only barrier in the kernel

    // ---- rare path: per-row exact kth (k=716) via wave-wide bitwise radix select.
    // Scores recomputed in fp32 VALU from the same bf16 q/k (selection is
    // self-consistent; boundary vs MFMA-rounded scores can drift ~1 ulp — unexercised here).
    if (need_sparse) {
        unsigned* ub = (unsigned*)&Pl[w][0];
        for (int r = 0; r < 16; ++r) {
            const unsigned short* qr = qg + (size_t)(i0 + r) * 64;
            for (int c = 0; c < 16; ++c) {
                const int col = c * 64 + l64;
                const unsigned short* kr = kg + (size_t)col * 64;
                float s = 0.f;
                for (int e = 0; e < 64; ++e) s += bf2f(qr[e]) * bf2f(kr[e]);
                unsigned uu = __float_as_uint(s * w_h + b_h);
                ub[col] = (uu & 0x80000000u) ? ~uu : (uu | 0x80000000u);
            }
            unsigned u[16];
            #pragma unroll
            for (int c = 0; c < 16; ++c) u[c] = ub[l64 + c * 64];
            unsigned act = 0xFFFFu, p = 0u;
            int kk = 716;
            for (int bit = 31; bit >= 0; --bit) {
                unsigned ones = 0u;
                #pragma unroll
                for (int c = 0; c < 16; ++c)
                    if (((act >> c) & 1u) && ((u[c] >> bit) & 1u)) ones |= (1u << c);
                int c1 = __popc(ones);
                for (int off = 32; off; off >>= 1) c1 += __shfl_xor(c1, off);
                if (kk <= c1) { p |= (1u << bit); act &= ones; }
                else          { kk -= c1; act &= ~ones; }
            }
            if (l64 == 0) kth_l[w][r] = p;
        }
    }
    unsigned kth_r[4] = {0u, 0u, 0u, 0u};
    if (need_sparse) {
        #pragma unroll
        for (int reg = 0; reg < 4; ++reg) kth_r[reg] = kth_l[w][quad * 4 + reg];
    }

    // Q A-fragments (persist across all chunks): A[m=ln][k=quad*8+j]
    const unsigned short* qrow = qg + (size_t)(i0 + ln) * 64 + quad * 8;
    const short8 aq0 = *(const short8*)qrow;          // e 0..31
    const short8 aq1 = *(const short8*)(qrow + 32);   // e 32..63

    float m_r[4] = {-3e38f, -3e38f, -3e38f, -3e38f};
    float l_r[4] = {0.f, 0.f, 0.f, 0.f};
    floatx4 accv[4];
    #pragma unroll
    for (int et = 0; et < 4; ++et) accv[et] = (floatx4){0.f, 0.f, 0.f, 0.f};
    unsigned short* Pw = &Pl[w][0];

    for (int jc = 0; jc < 8; ++jc) {
        const int j0 = jc << 7;
        // ---- QK^T chunk: 16 rows x 128 keys ----
        floatx4 sfr[8];
        #pragma unroll
        for (int nt = 0; nt < 8; ++nt) {
            const unsigned short* kr = kg + (size_t)(j0 + nt * 16 + ln) * 64 + quad * 8;
            const short8 b0 = *(const short8*)kr;
            const short8 b1 = *(const short8*)(kr + 32);
            floatx4 z = (floatx4){0.f, 0.f, 0.f, 0.f};
            z = MFMA16(aq0, b0, z);
            z = MFMA16(aq1, b1, z);
            sfr[nt] = z;
        }
        // ---- masking + row max (C layout: col = j0+nt*16+ln, row = i0+quad*4+reg) ----
        float rm[4] = {-3e38f, -3e38f, -3e38f, -3e38f};
        #pragma unroll
        for (int nt = 0; nt < 8; ++nt) {
            const int j = j0 + nt * 16 + ln;
            const bool mk0 = (mk[j] == 0);
            #pragma unroll
            for (int reg = 0; reg < 4; ++reg) {
                const int i = i0 + quad * 4 + reg;
                const float s = sfr[nt][reg];
                const bool loc = (j >= i - 16) && (j <= i + 16);
                bool sm = false;
                if (need_sparse) {
                    unsigned uu = __float_as_uint(s * w_h + b_h);
                    unsigned key = (uu & 0x80000000u) ? ~uu : (uu | 0x80000000u);
                    sm = key >= kth_r[reg];
                }
                bool allowed = loc ? (sm ? a11 : a10) : (sm ? a01 : a00);
                if (mk0) allowed = false;
                const float se = allowed ? s : -1e9f;
                sfr[nt][reg] = se;
                rm[reg] = fmaxf(rm[reg], se);
            }
        }
        #pragma unroll
        for (int reg = 0; reg < 4; ++reg) {
            float v = rm[reg];
            v = fmaxf(v, __shfl_xor(v, 1));
            v = fmaxf(v, __shfl_xor(v, 2));
            v = fmaxf(v, __shfl_xor(v, 4));
            v = fmaxf(v, __shfl_xor(v, 8));
            rm[reg] = v;
        }
        float alpha[4], rs[4];
        #pragma unroll
        for (int reg = 0; reg < 4; ++reg) {
            const float mn = fmaxf(m_r[reg], rm[reg]);
            alpha[reg] = __expf(m_r[reg] - mn);
            m_r[reg] = mn;
            rs[reg] = 0.f;
        }
        // ---- P = exp(s-m) -> bf16 -> wave-private LDS (transpose to A layout) ----
        #pragma unroll
        for (int nt = 0; nt < 8; ++nt)
            #pragma unroll
            for (int reg = 0; reg < 4; ++reg) {
                const float p = __expf(sfr[nt][reg] - m_r[reg]);
                rs[reg] += p;
                Pw[(quad * 4 + reg) * 144 + nt * 16 + ln] = f2bf(p);
            }
        #pragma unroll
        for (int reg = 0; reg < 4; ++reg) {
            float v = rs[reg];
            v += __shfl_xor(v, 1);
            v += __shfl_xor(v, 2);
            v += __shfl_xor(v, 4);
            v += __shfl_xor(v, 8);
            l_r[reg] = l_r[reg] * alpha[reg] + v;
        }
        // ---- P A-frags: A[m=ln][k=ks*32+quad*8+j] (in-wave DS ordering, no barrier) ----
        short8 pa[4];
        #pragma unroll
        for (int ks = 0; ks < 4; ++ks)
            pa[ks] = *(const short8*)&Pw[ln * 144 + ks * 32 + quad * 8];
        // ---- PV: out 16 rows x 64 elems, B from vT rows ----
        #pragma unroll
        for (int et = 0; et < 4; ++et) {
            floatx4 a = accv[et];
            a[0] *= alpha[0]; a[1] *= alpha[1]; a[2] *= alpha[2]; a[3] *= alpha[3];
            #pragma unroll
            for (int ks = 0; ks < 4; ++ks) {
                const unsigned short* vr = vg + (size_t)(et * 16 + ln) * 1024 + j0 + ks * 32 + quad * 8;
                const short8 bv = *(const short8*)vr;
                a = MFMA16(pa[ks], bv, a);
            }
            accv[et] = a;
        }
    }

    // ---- epilogue: normalize (or exact v[0] fallback), store bf16 ----
    #pragma unroll
    for (int et = 0; et < 4; ++et)
        #pragma unroll
        for (int reg = 0; reg < 4; ++reg) {
            const int row = i0 + quad * 4 + reg;
            float val;
            if (m_r[reg] <= -1e9f + 1e-6f)
                val = bf2f(vg[(size_t)(et * 16 + ln) * 1024]);   // v[0][e]
            else
                val = accv[et][reg] / l_r[reg];
            aout[((size_t)(b * 1024 + row)) * 512 + h * 64 + et * 16 + ln] = f2bf(val);
        }
}

// ============================================================
extern "C" void kernel_launch(void* const* d_in, const int* in_sizes, int n_in,
                              void* d_out, int out_size, void* d_ws, size_t ws_size,
                              hipStream_t stream) {
    const float* x     = (const float*)d_in[0];
    const int*   mask  = (const int*)d_in[1];
    const float* Wqkv  = (const float*)d_in[2];
    const float* Wproj = (const float*)d_in[3];
    const float* bproj = (const float*)d_in[4];
    const float* Wsel1 = (const float*)d_in[5];
    const float* bsel1 = (const float*)d_in[6];
    const float* Wsel2 = (const float*)d_in[7];
    const float* bsel2 = (const float*)d_in[8];
    const float* ltau  = (const float*)d_in[9];
    const float* sw    = (const float*)d_in[10];
    const float* sb    = (const float*)d_in[11];
    char* ws = (char*)d_ws;
    unsigned short* xb    = (unsigned short*)(ws + OFF_XB);
    unsigned short* wqkvb = (unsigned short*)(ws + OFF_WQKV);
    unsigned short* wprojb= (unsigned short*)(ws + OFF_WPROJ);
    unsigned short* q     = (unsigned short*)(ws + OFF_Q);
    unsigned short* k     = (unsigned short*)(ws + OFF_K);
    unsigned short* vT    = (unsigned short*)(ws + OFF_VT);
    unsigned short* attnb = (unsigned short*)(ws + OFF_AT);
    float* pw  = (float*)(ws + OFF_PW);
    float* par = (float*)(ws + OFF_PAR);
    float* out = (float*)d_out;
    (void)in_sizes; (void)n_in; (void)out_size; (void)ws_size;

    cvt_bf16<<<2048, 256, 0, stream>>>(x, xb, 524288);
    cvt_bf16<<<768, 256, 0, stream>>>(Wqkv, wqkvb, 196608);
    cvt_bf16<<<256, 256, 0, stream>>>(Wproj, wprojb, 65536);
    pool_stage1<<<dim3(4, 16), 256, 0, stream>>>(x, par);
    selector_kernel<<<4, 256, 0, stream>>>(par, Wsel1, bsel1, Wsel2, bsel2, ltau, pw);
    gemm_qkv<<<dim3(12, 32), 256, 0, stream>>>(xb, wqkvb, q, k, vT);
    attn_mfma<<<512, 256, 0, stream>>>(q, k, vT, mask, pw, sw, sb, attnb);
    gemm_proj<<<dim3(4, 32), 256, 0, stream>>>(attnb, wprojb, bproj, out);
}

// Round 3
// 231.224 us; speedup vs baseline: 3.0180x; 1.0853x over previous
//
#include <hip/hip_runtime.h>
#include <math.h>

typedef __attribute__((ext_vector_type(8))) short short8;
typedef __attribute__((ext_vector_type(4))) float floatx4;

#define MFMA16(a, b, c) __builtin_amdgcn_mfma_f32_16x16x32_bf16(a, b, c, 0, 0, 0)

// ---- fixed sizes: B=4 L=1024 D=512 H=8 HD=64 HID=256 half-win=16 KK=716 scale=1/8 ----

// ---- workspace byte offsets ----
#define OFF_XB    ((size_t)0)          // x bf16 [4096][512]
#define OFF_WQKV  ((size_t)4194304)    // Wqkv bf16 [1536][512]
#define OFF_WPROJ ((size_t)5767168)    // Wproj bf16 [512][512]
#define OFF_Q     ((size_t)6291456)    // q bf16 [32][1024][64] (scale folded)
#define OFF_K     ((size_t)10485760)   // k bf16 [32][1024][64]
#define OFF_VT    ((size_t)14680064)   // vT bf16 [32][64][1024]
#define OFF_AT    ((size_t)18874368)   // attn out bf16 [4096][512]
#define OFF_PW    ((size_t)23068672)   // pw fp32 [4][3]
#define OFF_PAR   ((size_t)23068928)   // pool partials fp32 [4][16][512]

__device__ __forceinline__ unsigned short f2bf(float f) {  // RNE
    unsigned u = __float_as_uint(f);
    return (unsigned short)((u + 0x7fffu + ((u >> 16) & 1u)) >> 16);
}
__device__ __forceinline__ float bf2f(unsigned short s) {
    return __uint_as_float((unsigned)s << 16);
}

// ============================================================
__global__ __launch_bounds__(256)
void cvt_bf16(const float* __restrict__ in, unsigned short* __restrict__ out, int n4)
{
    int i = blockIdx.x * 256 + threadIdx.x;
    if (i < n4) {
        float4 f = ((const float4*)in)[i];
        ushort4 o = make_ushort4(f2bf(f.x), f2bf(f.y), f2bf(f.z), f2bf(f.w));
        ((ushort4*)out)[i] = o;
    }
}

// ============================================================
// x -> bf16 conversion fused with mean-pool partial sums.
// grid (4,16), block 256.
// ============================================================
__global__ __launch_bounds__(256)
void cvt_pool_x(const float* __restrict__ x, unsigned short* __restrict__ xb,
                float* __restrict__ partial)
{
    const int b = blockIdx.x, lb = blockIdx.y, t = threadIdx.x;
    const size_t base = ((size_t)b * 1024 + lb * 64) * 512;
    float s0 = 0.f, s1 = 0.f;
    for (int l = 0; l < 64; ++l) {
        float v0 = x[base + (size_t)l * 512 + t];
        float v1 = x[base + (size_t)l * 512 + t + 256];
        s0 += v0; s1 += v1;
        xb[base + (size_t)l * 512 + t] = f2bf(v0);
        xb[base + (size_t)l * 512 + t + 256] = f2bf(v1);
    }
    partial[((size_t)b * 16 + lb) * 512 + t] = s0;
    partial[((size_t)b * 16 + lb) * 512 + t + 256] = s1;
}

// ============================================================
__global__ __launch_bounds__(256)
void selector_kernel(const float* __restrict__ partial,
                     const float* __restrict__ W1, const float* __restrict__ b1,
                     const float* __restrict__ W2, const float* __restrict__ b2,
                     const float* __restrict__ ltau, float* __restrict__ pwout)
{
    __shared__ float pooled[512];
    __shared__ float h1[256];
    __shared__ float lg[3];
    const int b = blockIdx.x, t = threadIdx.x;
    float s0 = 0.f, s1 = 0.f;
    for (int p = 0; p < 16; ++p) {
        s0 += partial[((size_t)b * 16 + p) * 512 + t];
        s1 += partial[((size_t)b * 16 + p) * 512 + t + 256];
    }
    pooled[t]       = s0 * (1.f / 1024.f);
    pooled[t + 256] = s1 * (1.f / 1024.f);
    __syncthreads();
    float acc = b1[t];
    const float* w1 = W1 + (size_t)t * 512;
    for (int d = 0; d < 512; d += 4) {
        float4 w4 = *(const float4*)(w1 + d);
        acc += w4.x * pooled[d] + w4.y * pooled[d + 1] + w4.z * pooled[d + 2] + w4.w * pooled[d + 3];
    }
    h1[t] = fmaxf(acc, 0.f);
    __syncthreads();
    if (t < 3) {
        float a = b2[t];
        const float* w2 = W2 + t * 256;
        for (int i = 0; i < 256; ++i) a += w2[i] * h1[i];
        float tauv = fminf(fmaxf(expf(ltau[0]), 1e-4f), 10.f);
        lg[t] = a / tauv;
    }
    __syncthreads();
    if (t == 0) {
        float m = fmaxf(lg[0], fmaxf(lg[1], lg[2]));
        float e0 = expf(lg[0] - m), e1 = expf(lg[1] - m), e2 = expf(lg[2] - m);
        float inv = 1.f / (e0 + e1 + e2);
        pwout[b * 3 + 0] = e0 * inv;
        pwout[b * 3 + 1] = e1 * inv;
        pwout[b * 3 + 2] = e2 * inv;
    }
}

// ============================================================
// QKV GEMM, bf16 MFMA, direct-from-global fragments, register double-buffer,
// LDS-transposed epilogue for coalesced q/k/vT stores.
// block 256 = 4 waves, wave tile 64x64. grid (12, 32): N=1536, M=4096, K=512.
// ============================================================
__global__ __launch_bounds__(256)
void gemm_qkv(const unsigned short* __restrict__ xb, const unsigned short* __restrict__ wb,
              unsigned short* __restrict__ qo, unsigned short* __restrict__ ko,
              unsigned short* __restrict__ vTo)
{
    __shared__ unsigned short tile[4][64 * 76];   // per-wave 64x64, stride 76
    const int t = threadIdx.x;
    const int w = t >> 6, l64 = t & 63;
    const int ln = l64 & 15, quad = l64 >> 4;
    const int m0 = blockIdx.y * 128 + (w & 1) * 64;
    const int n0 = blockIdx.x * 128 + (w >> 1) * 64;
    floatx4 acc[4][4];
    #pragma unroll
    for (int i = 0; i < 4; ++i)
        #pragma unroll
        for (int j = 0; j < 4; ++j) acc[i][j] = (floatx4){0.f, 0.f, 0.f, 0.f};

    const unsigned short* Ap = xb + (size_t)(m0 + ln) * 512 + quad * 8;
    const unsigned short* Bp = wb + (size_t)(n0 + ln) * 512 + quad * 8;

    short8 a0[4], b0[4], a1[4], b1[4];
    #pragma unroll
    for (int i = 0; i < 4; ++i) {
        a0[i] = *(const short8*)(Ap + (size_t)i * 8192);
        b0[i] = *(const short8*)(Bp + (size_t)i * 8192);
    }
    for (int ks = 0; ks < 16; ks += 2) {
        #pragma unroll
        for (int i = 0; i < 4; ++i) {
            a1[i] = *(const short8*)(Ap + (size_t)i * 8192 + (ks + 1) * 32);
            b1[i] = *(const short8*)(Bp + (size_t)i * 8192 + (ks + 1) * 32);
        }
        #pragma unroll
        for (int i = 0; i < 4; ++i)
            #pragma unroll
            for (int j = 0; j < 4; ++j)
                acc[i][j] = MFMA16(a0[i], b0[j], acc[i][j]);
        if (ks + 2 < 16) {
            #pragma unroll
            for (int i = 0; i < 4; ++i) {
                a0[i] = *(const short8*)(Ap + (size_t)i * 8192 + (ks + 2) * 32);
                b0[i] = *(const short8*)(Bp + (size_t)i * 8192 + (ks + 2) * 32);
            }
        }
        #pragma unroll
        for (int i = 0; i < 4; ++i)
            #pragma unroll
            for (int j = 0; j < 4; ++j)
                acc[i][j] = MFMA16(a1[i], b1[j], acc[i][j]);
    }

    // ---- epilogue: C frags -> wave-private LDS tile -> coalesced stores ----
    unsigned short* tw = &tile[w][0];
    const int which = n0 >> 9;            // 0=q 1=k 2=v (wave tile within one section)
    const int hh = (n0 >> 6) & 7;
    const int bb = m0 >> 10, ll0 = m0 & 1023;
    const int gg = bb * 8 + hh;

    if (which == 2) {
        // vT: tile[e][m]
        #pragma unroll
        for (int j = 0; j < 4; ++j)
            #pragma unroll
            for (int i = 0; i < 4; ++i)
                #pragma unroll
                for (int reg = 0; reg < 4; ++reg)
                    tw[(j * 16 + ln) * 76 + i * 16 + quad * 4 + reg] = f2bf(acc[i][j][reg]);
        unsigned short* dst = vTo + (size_t)gg * 64 * 1024 + ll0;
        #pragma unroll
        for (int it = 0; it < 16; ++it) {
            const int e = it * 4 + quad;
            ushort4 vv = *(const ushort4*)&tw[e * 76 + ln * 4];
            *(ushort4*)(dst + (size_t)e * 1024 + ln * 4) = vv;
        }
    } else {
        const float sc = (which == 0) ? 0.125f : 1.f;   // fold q scale (pow2, exact)
        #pragma unroll
        for (int j = 0; j < 4; ++j)
            #pragma unroll
            for (int i = 0; i < 4; ++i)
                #pragma unroll
                for (int reg = 0; reg < 4; ++reg)
                    tw[(i * 16 + quad * 4 + reg) * 76 + j * 16 + ln] = f2bf(acc[i][j][reg] * sc);
        unsigned short* dst = (which == 0 ? qo : ko) + ((size_t)gg * 1024 + ll0) * 64;
        #pragma unroll
        for (int it = 0; it < 16; ++it) {
            const int m = it * 4 + quad;
            ushort4 vv = *(const ushort4*)&tw[m * 76 + ln * 4];
            *(ushort4*)(dst + (size_t)m * 64 + ln * 4) = vv;
        }
    }
}

// ============================================================
// Proj GEMM: attn(bf16) @ Wproj^T + bias -> fp32. wave tile 32x64, grid (4,64).
// ============================================================
__global__ __launch_bounds__(256)
void gemm_proj(const unsigned short* __restrict__ ab, const unsigned short* __restrict__ wb,
               const float* __restrict__ bias, float* __restrict__ out)
{
    const int t = threadIdx.x;
    const int w = t >> 6, l64 = t & 63;
    const int ln = l64 & 15, quad = l64 >> 4;
    const int m0 = blockIdx.y * 64 + (w & 1) * 32;
    const int n0 = blockIdx.x * 128 + (w >> 1) * 64;
    floatx4 acc[2][4];
    #pragma unroll
    for (int i = 0; i < 2; ++i)
        #pragma unroll
        for (int j = 0; j < 4; ++j) acc[i][j] = (floatx4){0.f, 0.f, 0.f, 0.f};

    const unsigned short* Ap = ab + (size_t)(m0 + ln) * 512 + quad * 8;
    const unsigned short* Bp = wb + (size_t)(n0 + ln) * 512 + quad * 8;
    short8 a0[2], b0[4], a1[2], b1[4];
    #pragma unroll
    for (int i = 0; i < 2; ++i) a0[i] = *(const short8*)(Ap + (size_t)i * 8192);
    #pragma unroll
    for (int j = 0; j < 4; ++j) b0[j] = *(const short8*)(Bp + (size_t)j * 8192);
    for (int ks = 0; ks < 16; ks += 2) {
        #pragma unroll
        for (int i = 0; i < 2; ++i) a1[i] = *(const short8*)(Ap + (size_t)i * 8192 + (ks + 1) * 32);
        #pragma unroll
        for (int j = 0; j < 4; ++j) b1[j] = *(const short8*)(Bp + (size_t)j * 8192 + (ks + 1) * 32);
        #pragma unroll
        for (int i = 0; i < 2; ++i)
            #pragma unroll
            for (int j = 0; j < 4; ++j)
                acc[i][j] = MFMA16(a0[i], b0[j], acc[i][j]);
        if (ks + 2 < 16) {
            #pragma unroll
            for (int i = 0; i < 2; ++i) a0[i] = *(const short8*)(Ap + (size_t)i * 8192 + (ks + 2) * 32);
            #pragma unroll
            for (int j = 0; j < 4; ++j) b0[j] = *(const short8*)(Bp + (size_t)j * 8192 + (ks + 2) * 32);
        }
        #pragma unroll
        for (int i = 0; i < 2; ++i)
            #pragma unroll
            for (int j = 0; j < 4; ++j)
                acc[i][j] = MFMA16(a1[i], b1[j], acc[i][j]);
    }
    #pragma unroll
    for (int j = 0; j < 4; ++j) {
        const float bv = bias[n0 + j * 16 + ln];
        #pragma unroll
        for (int i = 0; i < 2; ++i)
            #pragma unroll
            for (int reg = 0; reg < 4; ++reg)
                out[(size_t)(m0 + i * 16 + quad * 4 + reg) * 512 + n0 + j * 16 + ln] =
                    acc[i][j][reg] + bv;
    }
}

// ============================================================
// Fused attention: block = 16 Q-rows, 4 waves split the key range (2 chunks of
// 128 each), online softmax per wave in registers, LDS merge at the end.
// grid 2048 (g = bid&31, rt = bid>>5), block 256. VGPR capped at 128 (16 waves/CU).
// ============================================================
__global__ __launch_bounds__(256, 4)
void attn_mfma(const unsigned short* __restrict__ qm, const unsigned short* __restrict__ km,
               const unsigned short* __restrict__ vT, const int* __restrict__ mask,
               const float* __restrict__ pw, const float* __restrict__ sw,
               const float* __restrict__ sb, unsigned short* __restrict__ aout)
{
    __shared__ int mk[1024];
    __shared__ unsigned short Pl[4][16 * 136];   // P transpose / radix ubuf (per wave)
    __shared__ float Opart[4][16][68];           // per-wave partial O
    __shared__ float msh[4][16], lsh[4][16];

    const int t = threadIdx.x;
    const int w = t >> 6, l64 = t & 63;
    const int ln = l64 & 15, quad = l64 >> 4;
    const int g = blockIdx.x & 31;
    const int rt = blockIdx.x >> 5;      // 0..63
    const int b = g >> 3, h = g & 7;
    const int i0 = rt * 16;

    const unsigned short* qg = qm + (size_t)g * 1024 * 64;
    const unsigned short* kg = km + (size_t)g * 1024 * 64;
    const unsigned short* vg = vT + (size_t)g * 64 * 1024;

    *(int4*)&mk[t * 4] = *(const int4*)(mask + b * 1024 + t * 4);

    const float pw0 = pw[b * 3 + 0], pw1 = pw[b * 3 + 1], pw2 = pw[b * 3 + 2];
    const bool a00 = pw1 > 0.05f;
    const bool a10 = (pw0 * 1.0f + pw1) > 0.05f;
    const bool a01 = (pw1 + pw2) > 0.05f;
    const bool a11 = ((pw0 * 1.0f + pw1) + pw2) > 0.05f;
    const bool need_sparse = (!a00 && a01) || (!a10 && a11);
    const bool flat_ok = (!need_sparse) && a00 && a10;  // allowed==true iff mk, exactly
    const float w_h = sw[h], b_h = sb[h];
    __syncthreads();

    // ---- rare path: exact per-row kth (k=716), bitwise radix select ----
    unsigned kth_r[4] = {0u, 0u, 0u, 0u};
    if (need_sparse) {
        unsigned* ub = (unsigned*)&Pl[w][0];
        for (int r = 0; r < 16; ++r) {
            const unsigned short* qr = qg + (size_t)(i0 + r) * 64;
            for (int c = 0; c < 16; ++c) {
                const int col = c * 64 + l64;
                const unsigned short* kr = kg + (size_t)col * 64;
                float s = 0.f;
                for (int e = 0; e < 64; ++e) s += bf2f(qr[e]) * bf2f(kr[e]);
                unsigned uu = __float_as_uint(s * w_h + b_h);
                ub[col] = (uu & 0x80000000u) ? ~uu : (uu | 0x80000000u);
            }
            unsigned u[16];
            #pragma unroll
            for (int c = 0; c < 16; ++c) u[c] = ub[l64 + c * 64];
            unsigned act = 0xFFFFu, p = 0u;
            int kk = 716;
            for (int bit = 31; bit >= 0; --bit) {
                unsigned ones = 0u;
                #pragma unroll
                for (int c = 0; c < 16; ++c)
                    if (((act >> c) & 1u) && ((u[c] >> bit) & 1u)) ones |= (1u << c);
                int c1 = __popc(ones);
                for (int off = 32; off; off >>= 1) c1 += __shfl_xor(c1, off);
                if (kk <= c1) { p |= (1u << bit); act &= ones; }
                else          { kk -= c1; act &= ~ones; }
            }
            if (l64 == 0) ((volatile unsigned*)ub)[1000 + 0] = 0;  // no-op keep shape
            if (l64 == 0) { msh[w][r] = __uint_as_float(p); }      // stash kth via msh temp
        }
        #pragma unroll
        for (int reg = 0; reg < 4; ++reg) kth_r[reg] = __float_as_uint(msh[w][quad * 4 + reg]);
    }

    // ---- Q A-fragments (rows i0..i0+15, shared by all waves) ----
    const unsigned short* qrow = qg + (size_t)(i0 + ln) * 64 + quad * 8;
    const short8 aq0 = *(const short8*)qrow;
    const short8 aq1 = *(const short8*)(qrow + 32);

    float m_r[4] = {-3e38f, -3e38f, -3e38f, -3e38f};
    float l_r[4] = {0.f, 0.f, 0.f, 0.f};
    floatx4 accv[4];
    #pragma unroll
    for (int et = 0; et < 4; ++et) accv[et] = (floatx4){0.f, 0.f, 0.f, 0.f};
    unsigned short* Pw = &Pl[w][0];

    for (int cc = 0; cc < 2; ++cc) {
        const int jc = w * 2 + cc;
        const int j0 = jc << 7;
        const bool mall = __all((mk[j0 + l64] != 0) && (mk[j0 + 64 + l64] != 0));
        const bool fast = flat_ok && mall;   // allowed==true for every element: skip mask VALU

        // ---- QK^T: 16 rows x 128 keys ----
        floatx4 sfr[8];
        #pragma unroll
        for (int nt = 0; nt < 8; ++nt) {
            const unsigned short* kr = kg + (size_t)(j0 + nt * 16 + ln) * 64 + quad * 8;
            const short8 b0 = *(const short8*)kr;
            const short8 b1 = *(const short8*)(kr + 32);
            floatx4 z = (floatx4){0.f, 0.f, 0.f, 0.f};
            z = MFMA16(aq0, b0, z);
            z = MFMA16(aq1, b1, z);
            sfr[nt] = z;
        }
        // prefetch first V group (hides under softmax VALU)
        short8 vb_cur[4], vb_nxt[4];
        #pragma unroll
        for (int ks = 0; ks < 4; ++ks)
            vb_cur[ks] = *(const short8*)(vg + (size_t)ln * 1024 + j0 + ks * 32 + quad * 8);

        // ---- masking + row max ----
        float rm[4] = {-3e38f, -3e38f, -3e38f, -3e38f};
        if (fast) {
            #pragma unroll
            for (int nt = 0; nt < 8; ++nt)
                #pragma unroll
                for (int reg = 0; reg < 4; ++reg) rm[reg] = fmaxf(rm[reg], sfr[nt][reg]);
        } else {
            #pragma unroll
            for (int nt = 0; nt < 8; ++nt) {
                const int j = j0 + nt * 16 + ln;
                const bool mk0 = (mk[j] == 0);
                #pragma unroll
                for (int reg = 0; reg < 4; ++reg) {
                    const int i = i0 + quad * 4 + reg;
                    const float s = sfr[nt][reg];
                    const bool loc = (j >= i - 16) && (j <= i + 16);
                    bool sm = false;
                    if (need_sparse) {
                        unsigned uu = __float_as_uint(s * w_h + b_h);
                        unsigned key = (uu & 0x80000000u) ? ~uu : (uu | 0x80000000u);
                        sm = key >= kth_r[reg];
                    }
                    bool allowed = loc ? (sm ? a11 : a10) : (sm ? a01 : a00);
                    if (mk0) allowed = false;
                    const float se = allowed ? s : -1e9f;
                    sfr[nt][reg] = se;
                    rm[reg] = fmaxf(rm[reg], se);
                }
            }
        }
        #pragma unroll
        for (int reg = 0; reg < 4; ++reg) {
            float v = rm[reg];
            v = fmaxf(v, __shfl_xor(v, 1));
            v = fmaxf(v, __shfl_xor(v, 2));
            v = fmaxf(v, __shfl_xor(v, 4));
            v = fmaxf(v, __shfl_xor(v, 8));
            rm[reg] = v;
        }
        float alpha[4], rs[4];
        #pragma unroll
        for (int reg = 0; reg < 4; ++reg) {
            const float mn = fmaxf(m_r[reg], rm[reg]);
            alpha[reg] = __expf(m_r[reg] - mn);
            m_r[reg] = mn;
            rs[reg] = 0.f;
        }
        // ---- P = exp(s-m) -> bf16 -> wave-private LDS (C->A transpose, stride 136) ----
        #pragma unroll
        for (int nt = 0; nt < 8; ++nt)
            #pragma unroll
            for (int reg = 0; reg < 4; ++reg) {
                const float p = __expf(sfr[nt][reg] - m_r[reg]);
                rs[reg] += p;
                Pw[(quad * 4 + reg) * 136 + nt * 16 + ln] = f2bf(p);
            }
        #pragma unroll
        for (int reg = 0; reg < 4; ++reg) {
            float v = rs[reg];
            v += __shfl_xor(v, 1);
            v += __shfl_xor(v, 2);
            v += __shfl_xor(v, 4);
            v += __shfl_xor(v, 8);
            l_r[reg] = l_r[reg] * alpha[reg] + v;
        }
        short8 pa[4];
        #pragma unroll
        for (int ks = 0; ks < 4; ++ks)
            pa[ks] = *(const short8*)&Pw[ln * 136 + ks * 32 + quad * 8];
        // ---- PV with et-pipelined V fragment loads ----
        #pragma unroll
        for (int et = 0; et < 4; ++et) {
            if (et < 3) {
                #pragma unroll
                for (int ks = 0; ks < 4; ++ks)
                    vb_nxt[ks] = *(const short8*)(vg + (size_t)((et + 1) * 16 + ln) * 1024 +
                                                  j0 + ks * 32 + quad * 8);
            }
            floatx4 a = accv[et];
            a[0] *= alpha[0]; a[1] *= alpha[1]; a[2] *= alpha[2]; a[3] *= alpha[3];
            #pragma unroll
            for (int ks = 0; ks < 4; ++ks) a = MFMA16(pa[ks], vb_cur[ks], a);
            accv[et] = a;
            #pragma unroll
            for (int ks = 0; ks < 4; ++ks) vb_cur[ks] = vb_nxt[ks];
        }
    }

    // ---- write per-wave partials ----
    #pragma unroll
    for (int et = 0; et < 4; ++et)
        #pragma unroll
        for (int reg = 0; reg < 4; ++reg)
            Opart[w][quad * 4 + reg][et * 16 + ln] = accv[et][reg];
    if (ln == 0) {
        #pragma unroll
        for (int reg = 0; reg < 4; ++reg) {
            msh[w][quad * 4 + reg] = m_r[reg];
            lsh[w][quad * 4 + reg] = l_r[reg];
        }
    }
    __syncthreads();

    // ---- merge 4 wave-partials -> final output (16 rows x 64 cols by 256 thr) ----
    {
        const int r = t >> 4, cb = (t & 15) * 4;
        float M = fmaxf(fmaxf(msh[0][r], msh[1][r]), fmaxf(msh[2][r], msh[3][r]));
        float L = 0.f;
        float4 o = make_float4(0.f, 0.f, 0.f, 0.f);
        #pragma unroll
        for (int wv = 0; wv < 4; ++wv) {
            const float sc = __expf(msh[wv][r] - M);
            L += lsh[wv][r] * sc;
            float4 ov = *(const float4*)&Opart[wv][r][cb];
            o.x += ov.x * sc; o.y += ov.y * sc; o.z += ov.z * sc; o.w += ov.w * sc;
        }
        ushort4 res;
        if (M <= -1e9f + 1e-6f) {
            res.x = vg[(size_t)(cb + 0) * 1024];
            res.y = vg[(size_t)(cb + 1) * 1024];
            res.z = vg[(size_t)(cb + 2) * 1024];
            res.w = vg[(size_t)(cb + 3) * 1024];
        } else {
            const float inv = 1.f / L;
            res.x = f2bf(o.x * inv); res.y = f2bf(o.y * inv);
            res.z = f2bf(o.z * inv); res.w = f2bf(o.w * inv);
        }
        *(ushort4*)&aout[((size_t)(b * 1024 + i0 + r)) * 512 + h * 64 + cb] = res;
    }
}

// ============================================================
extern "C" void kernel_launch(void* const* d_in, const int* in_sizes, int n_in,
                              void* d_out, int out_size, void* d_ws, size_t ws_size,
                              hipStream_t stream) {
    const float* x     = (const float*)d_in[0];
    const int*   mask  = (const int*)d_in[1];
    const float* Wqkv  = (const float*)d_in[2];
    const float* Wproj = (const float*)d_in[3];
    const float* bproj = (const float*)d_in[4];
    const float* Wsel1 = (const float*)d_in[5];
    const float* bsel1 = (const float*)d_in[6];
    const float* Wsel2 = (const float*)d_in[7];
    const float* bsel2 = (const float*)d_in[8];
    const float* ltau  = (const float*)d_in[9];
    const float* sw    = (const float*)d_in[10];
    const float* sb    = (const float*)d_in[11];
    char* ws = (char*)d_ws;
    unsigned short* xb     = (unsigned short*)(ws + OFF_XB);
    unsigned short* wqkvb  = (unsigned short*)(ws + OFF_WQKV);
    unsigned short* wprojb = (unsigned short*)(ws + OFF_WPROJ);
    unsigned short* q      = (unsigned short*)(ws + OFF_Q);
    unsigned short* k      = (unsigned short*)(ws + OFF_K);
    unsigned short* vT     = (unsigned short*)(ws + OFF_VT);
    unsigned short* attnb  = (unsigned short*)(ws + OFF_AT);
    float* pw  = (float*)(ws + OFF_PW);
    float* par = (float*)(ws + OFF_PAR);
    float* out = (float*)d_out;
    (void)in_sizes; (void)n_in; (void)out_size; (void)ws_size;

    cvt_pool_x<<<dim3(4, 16), 256, 0, stream>>>(x, xb, par);
    cvt_bf16<<<768, 256, 0, stream>>>(Wqkv, wqkvb, 196608);
    cvt_bf16<<<256, 256, 0, stream>>>(Wproj, wprojb, 65536);
    selector_kernel<<<4, 256, 0, stream>>>(par, Wsel1, bsel1, Wsel2, bsel2, ltau, pw);
    gemm_qkv<<<dim3(12, 32), 256, 0, stream>>>(xb, wqkvb, q, k, vT);
    attn_mfma<<<2048, 256, 0, stream>>>(q, k, vT, mask, pw, sw, sb, attnb);
    gemm_proj<<<dim3(4, 64), 256, 0, stream>>>(attnb, wprojb, bproj, out);
}

// Round 4
// 219.396 us; speedup vs baseline: 3.1807x; 1.0539x over previous
//
#include <hip/hip_runtime.h>
#include <math.h>

typedef __attribute__((ext_vector_type(8))) short short8;
typedef __attribute__((ext_vector_type(4))) float floatx4;

#define MFMA16(a, b, c) __builtin_amdgcn_mfma_f32_16x16x32_bf16(a, b, c, 0, 0, 0)

// ---- fixed sizes: B=4 L=1024 D=512 H=8 HD=64 HID=256 half-win=16 KK=716 scale=1/8 ----

// ---- workspace byte offsets ----
#define OFF_XB    ((size_t)0)          // x bf16 [4096][512]
#define OFF_WQKV  ((size_t)4194304)    // Wqkv bf16 [1536][512]
#define OFF_WPROJ ((size_t)5767168)    // Wproj bf16 [512][512]
#define OFF_Q     ((size_t)6291456)    // q bf16 [32][1024][64] (scale folded)
#define OFF_K     ((size_t)10485760)   // k bf16 [32][1024][64]
#define OFF_VT    ((size_t)14680064)   // vT bf16 [32][64][1024]
#define OFF_AT    ((size_t)18874368)   // attn out bf16 [4096][512]
#define OFF_PW    ((size_t)23068672)   // pw fp32 [4][3]
#define OFF_PAR   ((size_t)23069696)   // pool partials fp32 [4][64][512] (512KB)

__device__ __forceinline__ unsigned short f2bf(float f) {  // RNE
    unsigned u = __float_as_uint(f);
    return (unsigned short)((u + 0x7fffu + ((u >> 16) & 1u)) >> 16);
}
__device__ __forceinline__ float bf2f(unsigned short s) {
    return __uint_as_float((unsigned)s << 16);
}

// ============================================================
// Both weight conversions in one launch. grid 1024, block 256.
// ============================================================
__global__ __launch_bounds__(256)
void cvt_w(const float* __restrict__ wqkv, const float* __restrict__ wproj,
           unsigned short* __restrict__ oq, unsigned short* __restrict__ op)
{
    int i = blockIdx.x * 256 + threadIdx.x;
    if (i < 196608) {
        float4 f = ((const float4*)wqkv)[i];
        ((ushort4*)oq)[i] = make_ushort4(f2bf(f.x), f2bf(f.y), f2bf(f.z), f2bf(f.w));
    } else {
        int j = i - 196608;   // < 65536
        float4 f = ((const float4*)wproj)[j];
        ((ushort4*)op)[j] = make_ushort4(f2bf(f.x), f2bf(f.y), f2bf(f.z), f2bf(f.w));
    }
}

// ============================================================
// x -> bf16 fused with mean-pool partials. grid (4,64), block 256 (16 rows/block).
// ============================================================
__global__ __launch_bounds__(256)
void cvt_pool_x(const float* __restrict__ x, unsigned short* __restrict__ xb,
                float* __restrict__ partial)
{
    const int b = blockIdx.x, lb = blockIdx.y, t = threadIdx.x;
    const size_t base = ((size_t)b * 1024 + lb * 16) * 512;
    float s0 = 0.f, s1 = 0.f;
    #pragma unroll 4
    for (int l = 0; l < 16; ++l) {
        float v0 = x[base + (size_t)l * 512 + t];
        float v1 = x[base + (size_t)l * 512 + t + 256];
        s0 += v0; s1 += v1;
        xb[base + (size_t)l * 512 + t] = f2bf(v0);
        xb[base + (size_t)l * 512 + t + 256] = f2bf(v1);
    }
    partial[((size_t)b * 64 + lb) * 512 + t] = s0;
    partial[((size_t)b * 64 + lb) * 512 + t + 256] = s1;
}

// ============================================================
__global__ __launch_bounds__(256)
void selector_kernel(const float* __restrict__ partial,
                     const float* __restrict__ W1, const float* __restrict__ b1,
                     const float* __restrict__ W2, const float* __restrict__ b2,
                     const float* __restrict__ ltau, float* __restrict__ pwout)
{
    __shared__ float pooled[512];
    __shared__ float h1[256];
    __shared__ float lg[3];
    const int b = blockIdx.x, t = threadIdx.x;
    float s0 = 0.f, s1 = 0.f;
    for (int p = 0; p < 64; ++p) {
        s0 += partial[((size_t)b * 64 + p) * 512 + t];
        s1 += partial[((size_t)b * 64 + p) * 512 + t + 256];
    }
    pooled[t]       = s0 * (1.f / 1024.f);
    pooled[t + 256] = s1 * (1.f / 1024.f);
    __syncthreads();
    float acc = b1[t];
    const float* w1 = W1 + (size_t)t * 512;
    for (int d = 0; d < 512; d += 4) {
        float4 w4 = *(const float4*)(w1 + d);
        acc += w4.x * pooled[d] + w4.y * pooled[d + 1] + w4.z * pooled[d + 2] + w4.w * pooled[d + 3];
    }
    h1[t] = fmaxf(acc, 0.f);
    __syncthreads();
    if (t < 3) {
        float a = b2[t];
        const float* w2 = W2 + t * 256;
        for (int i = 0; i < 256; ++i) a += w2[i] * h1[i];
        float tauv = fminf(fmaxf(expf(ltau[0]), 1e-4f), 10.f);
        lg[t] = a / tauv;
    }
    __syncthreads();
    if (t == 0) {
        float m = fmaxf(lg[0], fmaxf(lg[1], lg[2]));
        float e0 = expf(lg[0] - m), e1 = expf(lg[1] - m), e2 = expf(lg[2] - m);
        float inv = 1.f / (e0 + e1 + e2);
        pwout[b * 3 + 0] = e0 * inv;
        pwout[b * 3 + 1] = e1 * inv;
        pwout[b * 3 + 2] = e2 * inv;
    }
}

// ============================================================
// QKV GEMM, bf16 MFMA, direct-from-global fragments, register double-buffer,
// LDS-transposed epilogue for coalesced q/k/vT stores.
// block 256 = 4 waves, wave tile 64x64. grid (12, 32): N=1536, M=4096, K=512.
// ============================================================
__global__ __launch_bounds__(256)
void gemm_qkv(const unsigned short* __restrict__ xb, const unsigned short* __restrict__ wb,
              unsigned short* __restrict__ qo, unsigned short* __restrict__ ko,
              unsigned short* __restrict__ vTo)
{
    __shared__ unsigned short tile[4][64 * 76];   // per-wave 64x64, stride 76
    const int t = threadIdx.x;
    const int w = t >> 6, l64 = t & 63;
    const int ln = l64 & 15, quad = l64 >> 4;
    const int m0 = blockIdx.y * 128 + (w & 1) * 64;
    const int n0 = blockIdx.x * 128 + (w >> 1) * 64;
    floatx4 acc[4][4];
    #pragma unroll
    for (int i = 0; i < 4; ++i)
        #pragma unroll
        for (int j = 0; j < 4; ++j) acc[i][j] = (floatx4){0.f, 0.f, 0.f, 0.f};

    const unsigned short* Ap = xb + (size_t)(m0 + ln) * 512 + quad * 8;
    const unsigned short* Bp = wb + (size_t)(n0 + ln) * 512 + quad * 8;

    short8 a0[4], b0[4], a1[4], b1[4];
    #pragma unroll
    for (int i = 0; i < 4; ++i) {
        a0[i] = *(const short8*)(Ap + (size_t)i * 8192);
        b0[i] = *(const short8*)(Bp + (size_t)i * 8192);
    }
    for (int ks = 0; ks < 16; ks += 2) {
        #pragma unroll
        for (int i = 0; i < 4; ++i) {
            a1[i] = *(const short8*)(Ap + (size_t)i * 8192 + (ks + 1) * 32);
            b1[i] = *(const short8*)(Bp + (size_t)i * 8192 + (ks + 1) * 32);
        }
        #pragma unroll
        for (int i = 0; i < 4; ++i)
            #pragma unroll
            for (int j = 0; j < 4; ++j)
                acc[i][j] = MFMA16(a0[i], b0[j], acc[i][j]);
        if (ks + 2 < 16) {
            #pragma unroll
            for (int i = 0; i < 4; ++i) {
                a0[i] = *(const short8*)(Ap + (size_t)i * 8192 + (ks + 2) * 32);
                b0[i] = *(const short8*)(Bp + (size_t)i * 8192 + (ks + 2) * 32);
            }
        }
        #pragma unroll
        for (int i = 0; i < 4; ++i)
            #pragma unroll
            for (int j = 0; j < 4; ++j)
                acc[i][j] = MFMA16(a1[i], b1[j], acc[i][j]);
    }

    // ---- epilogue: C frags -> wave-private LDS tile -> coalesced stores ----
    unsigned short* tw = &tile[w][0];
    const int which = n0 >> 9;            // 0=q 1=k 2=v
    const int hh = (n0 >> 6) & 7;
    const int bb = m0 >> 10, ll0 = m0 & 1023;
    const int gg = bb * 8 + hh;

    if (which == 2) {
        // vT: tile[e][m]
        #pragma unroll
        for (int j = 0; j < 4; ++j)
            #pragma unroll
            for (int i = 0; i < 4; ++i)
                #pragma unroll
                for (int reg = 0; reg < 4; ++reg)
                    tw[(j * 16 + ln) * 76 + i * 16 + quad * 4 + reg] = f2bf(acc[i][j][reg]);
        unsigned short* dst = vTo + (size_t)gg * 64 * 1024 + ll0;
        #pragma unroll
        for (int it = 0; it < 16; ++it) {
            const int e = it * 4 + quad;
            ushort4 vv = *(const ushort4*)&tw[e * 76 + ln * 4];
            *(ushort4*)(dst + (size_t)e * 1024 + ln * 4) = vv;
        }
    } else {
        const float sc = (which == 0) ? 0.125f : 1.f;   // fold q scale (pow2, exact)
        #pragma unroll
        for (int j = 0; j < 4; ++j)
            #pragma unroll
            for (int i = 0; i < 4; ++i)
                #pragma unroll
                for (int reg = 0; reg < 4; ++reg)
                    tw[(i * 16 + quad * 4 + reg) * 76 + j * 16 + ln] = f2bf(acc[i][j][reg] * sc);
        unsigned short* dst = (which == 0 ? qo : ko) + ((size_t)gg * 1024 + ll0) * 64;
        #pragma unroll
        for (int it = 0; it < 16; ++it) {
            const int m = it * 4 + quad;
            ushort4 vv = *(const ushort4*)&tw[m * 76 + ln * 4];
            *(ushort4*)(dst + (size_t)m * 64 + ln * 4) = vv;
        }
    }
}

// ============================================================
// Proj GEMM: attn(bf16) @ Wproj^T + bias -> fp32. wave tile 32x64, grid (4,64).
// ============================================================
__global__ __launch_bounds__(256)
void gemm_proj(const unsigned short* __restrict__ ab, const unsigned short* __restrict__ wb,
               const float* __restrict__ bias, float* __restrict__ out)
{
    const int t = threadIdx.x;
    const int w = t >> 6, l64 = t & 63;
    const int ln = l64 & 15, quad = l64 >> 4;
    const int m0 = blockIdx.y * 64 + (w & 1) * 32;
    const int n0 = blockIdx.x * 128 + (w >> 1) * 64;
    floatx4 acc[2][4];
    #pragma unroll
    for (int i = 0; i < 2; ++i)
        #pragma unroll
        for (int j = 0; j < 4; ++j) acc[i][j] = (floatx4){0.f, 0.f, 0.f, 0.f};

    const unsigned short* Ap = ab + (size_t)(m0 + ln) * 512 + quad * 8;
    const unsigned short* Bp = wb + (size_t)(n0 + ln) * 512 + quad * 8;
    short8 a0[2], b0[4], a1[2], b1[4];
    #pragma unroll
    for (int i = 0; i < 2; ++i) a0[i] = *(const short8*)(Ap + (size_t)i * 8192);
    #pragma unroll
    for (int j = 0; j < 4; ++j) b0[j] = *(const short8*)(Bp + (size_t)j * 8192);
    for (int ks = 0; ks < 16; ks += 2) {
        #pragma unroll
        for (int i = 0; i < 2; ++i) a1[i] = *(const short8*)(Ap + (size_t)i * 8192 + (ks + 1) * 32);
        #pragma unroll
        for (int j = 0; j < 4; ++j) b1[j] = *(const short8*)(Bp + (size_t)j * 8192 + (ks + 1) * 32);
        #pragma unroll
        for (int i = 0; i < 2; ++i)
            #pragma unroll
            for (int j = 0; j < 4; ++j)
                acc[i][j] = MFMA16(a0[i], b0[j], acc[i][j]);
        if (ks + 2 < 16) {
            #pragma unroll
            for (int i = 0; i < 2; ++i) a0[i] = *(const short8*)(Ap + (size_t)i * 8192 + (ks + 2) * 32);
            #pragma unroll
            for (int j = 0; j < 4; ++j) b0[j] = *(const short8*)(Bp + (size_t)j * 8192 + (ks + 2) * 32);
        }
        #pragma unroll
        for (int i = 0; i < 2; ++i)
            #pragma unroll
            for (int j = 0; j < 4; ++j)
                acc[i][j] = MFMA16(a1[i], b1[j], acc[i][j]);
    }
    #pragma unroll
    for (int j = 0; j < 4; ++j) {
        const float bv = bias[n0 + j * 16 + ln];
        #pragma unroll
        for (int i = 0; i < 2; ++i)
            #pragma unroll
            for (int reg = 0; reg < 4; ++reg)
                out[(size_t)(m0 + i * 16 + quad * 4 + reg) * 512 + n0 + j * 16 + ln] =
                    acc[i][j][reg] + bv;
    }
}

// ============================================================
// Fused attention. block = 16 Q-rows; 4 waves each take 2 of the 8 key-chunks;
// LDS merge at the end. grid 2048, block 256.
// No min-waves bound: the kernel batch-loads all 16 K-fragments of a chunk
// (16 global loads in flight) — needs ~160 VGPR; round-3's (256,4) bound
// squeezed it to 64 VGPR and serialized every load.
// LDS: P-transpose region overlaid with O-partial region (both 4352B/wave).
// ============================================================
__global__ __launch_bounds__(256)
void attn_mfma(const unsigned short* __restrict__ qm, const unsigned short* __restrict__ km,
               const unsigned short* __restrict__ vT, const int* __restrict__ mask,
               const float* __restrict__ pw, const float* __restrict__ sw,
               const float* __restrict__ sb, unsigned short* __restrict__ aout)
{
    __shared__ int mk[1024];
    __shared__ float PO[4][16][68];   // per-wave union: P bf16[16][136] / radix ubuf / Opart f32[16][68]
    __shared__ float msh[4][16], lsh[4][16];
    __shared__ unsigned kths[4][16];

    const int t = threadIdx.x;
    const int w = t >> 6, l64 = t & 63;
    const int ln = l64 & 15, quad = l64 >> 4;
    const int g = blockIdx.x & 31;       // (b,h); g%8 keeps one g's blocks on one XCD
    const int rt = blockIdx.x >> 5;      // 0..63
    const int b = g >> 3, h = g & 7;
    const int i0 = rt * 16;

    const unsigned short* qg = qm + (size_t)g * 1024 * 64;
    const unsigned short* kg = km + (size_t)g * 1024 * 64;
    const unsigned short* vg = vT + (size_t)g * 64 * 1024;

    *(int4*)&mk[t * 4] = *(const int4*)(mask + b * 1024 + t * 4);

    const float pw0 = pw[b * 3 + 0], pw1 = pw[b * 3 + 1], pw2 = pw[b * 3 + 2];
    const bool a00 = pw1 > 0.05f;
    const bool a10 = (pw0 * 1.0f + pw1) > 0.05f;
    const bool a01 = (pw1 + pw2) > 0.05f;
    const bool a11 = ((pw0 * 1.0f + pw1) + pw2) > 0.05f;
    const bool need_sparse = (!a00 && a01) || (!a10 && a11);
    const bool flat_ok = (!need_sparse) && a00 && a10;  // allowed==true iff mk!=0, exactly
    const float w_h = sw[h], b_h = sb[h];
    __syncthreads();

    // ---- rare path: exact per-row kth (k=716), bitwise radix select ----
    unsigned kth_r[4] = {0u, 0u, 0u, 0u};
    if (need_sparse) {
        unsigned* ub = (unsigned*)&PO[w][0][0];
        for (int r = 0; r < 16; ++r) {
            const unsigned short* qr = qg + (size_t)(i0 + r) * 64;
            for (int c = 0; c < 16; ++c) {
                const int col = c * 64 + l64;
                const unsigned short* kr = kg + (size_t)col * 64;
                float s = 0.f;
                for (int e = 0; e < 64; ++e) s += bf2f(qr[e]) * bf2f(kr[e]);
                unsigned uu = __float_as_uint(s * w_h + b_h);
                ub[col] = (uu & 0x80000000u) ? ~uu : (uu | 0x80000000u);
            }
            unsigned u[16];
            #pragma unroll
            for (int c = 0; c < 16; ++c) u[c] = ub[l64 + c * 64];
            unsigned act = 0xFFFFu, p = 0u;
            int kk = 716;
            for (int bit = 31; bit >= 0; --bit) {
                unsigned ones = 0u;
                #pragma unroll
                for (int c = 0; c < 16; ++c)
                    if (((act >> c) & 1u) && ((u[c] >> bit) & 1u)) ones |= (1u << c);
                int c1 = __popc(ones);
                for (int off = 32; off; off >>= 1) c1 += __shfl_xor(c1, off);
                if (kk <= c1) { p |= (1u << bit); act &= ones; }
                else          { kk -= c1; act &= ~ones; }
            }
            if (l64 == 0) kths[w][r] = p;
        }
        #pragma unroll
        for (int reg = 0; reg < 4; ++reg) kth_r[reg] = kths[w][quad * 4 + reg];
    }

    // ---- Q A-fragments (rows i0..i0+15, same for all waves) ----
    const unsigned short* qrow = qg + (size_t)(i0 + ln) * 64 + quad * 8;
    const short8 aq0 = *(const short8*)qrow;
    const short8 aq1 = *(const short8*)(qrow + 32);

    float m_r[4] = {-3e38f, -3e38f, -3e38f, -3e38f};
    float l_r[4] = {0.f, 0.f, 0.f, 0.f};
    floatx4 accv[4];
    #pragma unroll
    for (int et = 0; et < 4; ++et) accv[et] = (floatx4){0.f, 0.f, 0.f, 0.f};
    unsigned short* Pw = (unsigned short*)&PO[w][0][0];   // stride 136 shorts

    #pragma unroll
    for (int cc = 0; cc < 2; ++cc) {
        const int j0 = (w * 2 + cc) << 7;
        const bool mall = __all((mk[j0 + l64] != 0) && (mk[j0 + 64 + l64] != 0));
        const bool fast = flat_ok && mall;

        // ---- batch-issue all 16 K-fragment loads (one latency, not eight) ----
        const unsigned short* kbase = kg + (size_t)(j0 + ln) * 64 + quad * 8;
        short8 kb0[8], kb1[8];
        #pragma unroll
        for (int nt = 0; nt < 8; ++nt) {
            kb0[nt] = *(const short8*)(kbase + (size_t)nt * 1024);
            kb1[nt] = *(const short8*)(kbase + (size_t)nt * 1024 + 32);
        }
        // V prefetch for et=0 (in flight with the K loads)
        short8 vb_cur[4], vb_nxt[4];
        #pragma unroll
        for (int ks = 0; ks < 4; ++ks)
            vb_cur[ks] = *(const short8*)(vg + (size_t)ln * 1024 + j0 + ks * 32 + quad * 8);

        // ---- QK^T: 16 rows x 128 keys ----
        floatx4 sfr[8];
        #pragma unroll
        for (int nt = 0; nt < 8; ++nt) {
            floatx4 z = (floatx4){0.f, 0.f, 0.f, 0.f};
            z = MFMA16(aq0, kb0[nt], z);
            z = MFMA16(aq1, kb1[nt], z);
            sfr[nt] = z;
        }

        // ---- masking + row max (C layout: col = j0+nt*16+ln, row = i0+quad*4+reg) ----
        float rm[4] = {-3e38f, -3e38f, -3e38f, -3e38f};
        if (fast) {
            #pragma unroll
            for (int nt = 0; nt < 8; ++nt)
                #pragma unroll
                for (int reg = 0; reg < 4; ++reg) rm[reg] = fmaxf(rm[reg], sfr[nt][reg]);
        } else {
            #pragma unroll
            for (int nt = 0; nt < 8; ++nt) {
                const int j = j0 + nt * 16 + ln;
                const bool mk0 = (mk[j] == 0);
                #pragma unroll
                for (int reg = 0; reg < 4; ++reg) {
                    const int i = i0 + quad * 4 + reg;
                    const float s = sfr[nt][reg];
                    const bool loc = (j >= i - 16) && (j <= i + 16);
                    bool sm = false;
                    if (need_sparse) {
                        unsigned uu = __float_as_uint(s * w_h + b_h);
                        unsigned key = (uu & 0x80000000u) ? ~uu : (uu | 0x80000000u);
                        sm = key >= kth_r[reg];
                    }
                    bool allowed = loc ? (sm ? a11 : a10) : (sm ? a01 : a00);
                    if (mk0) allowed = false;
                    const float se = allowed ? s : -1e9f;
                    sfr[nt][reg] = se;
                    rm[reg] = fmaxf(rm[reg], se);
                }
            }
        }
        #pragma unroll
        for (int reg = 0; reg < 4; ++reg) {
            float v = rm[reg];
            v = fmaxf(v, __shfl_xor(v, 1));
            v = fmaxf(v, __shfl_xor(v, 2));
            v = fmaxf(v, __shfl_xor(v, 4));
            v = fmaxf(v, __shfl_xor(v, 8));
            rm[reg] = v;
        }
        float alpha[4], rs[4];
        #pragma unroll
        for (int reg = 0; reg < 4; ++reg) {
            const float mn = fmaxf(m_r[reg], rm[reg]);
            alpha[reg] = __expf(m_r[reg] - mn);
            m_r[reg] = mn;
            rs[reg] = 0.f;
        }
        // ---- P = exp(s-m) -> bf16 -> wave-private LDS (C->A transpose) ----
        #pragma unroll
        for (int nt = 0; nt < 8; ++nt)
            #pragma unroll
            for (int reg = 0; reg < 4; ++reg) {
                const float p = __expf(sfr[nt][reg] - m_r[reg]);
                rs[reg] += p;
                Pw[(quad * 4 + reg) * 136 + nt * 16 + ln] = f2bf(p);
            }
        #pragma unroll
        for (int reg = 0; reg < 4; ++reg) {
            float v = rs[reg];
            v += __shfl_xor(v, 1);
            v += __shfl_xor(v, 2);
            v += __shfl_xor(v, 4);
            v += __shfl_xor(v, 8);
            l_r[reg] = l_r[reg] * alpha[reg] + v;
        }
        short8 pa[4];
        #pragma unroll
        for (int ks = 0; ks < 4; ++ks)
            pa[ks] = *(const short8*)&Pw[ln * 136 + ks * 32 + quad * 8];
        // ---- PV with et-pipelined V fragment loads ----
        #pragma unroll
        for (int et = 0; et < 4; ++et) {
            if (et < 3) {
                #pragma unroll
                for (int ks = 0; ks < 4; ++ks)
                    vb_nxt[ks] = *(const short8*)(vg + (size_t)((et + 1) * 16 + ln) * 1024 +
                                                  j0 + ks * 32 + quad * 8);
            }
            floatx4 a = accv[et];
            a[0] *= alpha[0]; a[1] *= alpha[1]; a[2] *= alpha[2]; a[3] *= alpha[3];
            #pragma unroll
            for (int ks = 0; ks < 4; ++ks) a = MFMA16(pa[ks], vb_cur[ks], a);
            accv[et] = a;
            #pragma unroll
            for (int ks = 0; ks < 4; ++ks) vb_cur[ks] = vb_nxt[ks];
        }
    }

    // ---- per-wave partials into the (now-free) P region ----
    #pragma unroll
    for (int et = 0; et < 4; ++et)
        #pragma unroll
        for (int reg = 0; reg < 4; ++reg)
            PO[w][quad * 4 + reg][et * 16 + ln] = accv[et][reg];
    if (ln == 0) {
        #pragma unroll
        for (int reg = 0; reg < 4; ++reg) {
            msh[w][quad * 4 + reg] = m_r[reg];
            lsh[w][quad * 4 + reg] = l_r[reg];
        }
    }
    __syncthreads();

    // ---- merge 4 wave-partials -> final output (16 rows x 64 cols by 256 thr) ----
    {
        const int r = t >> 4, cb = (t & 15) * 4;
        float M = fmaxf(fmaxf(msh[0][r], msh[1][r]), fmaxf(msh[2][r], msh[3][r]));
        float L = 0.f;
        float4 o = make_float4(0.f, 0.f, 0.f, 0.f);
        #pragma unroll
        for (int wv = 0; wv < 4; ++wv) {
            const float sc = __expf(msh[wv][r] - M);
            L += lsh[wv][r] * sc;
            float4 ov = *(const float4*)&PO[wv][r][cb];
            o.x += ov.x * sc; o.y += ov.y * sc; o.z += ov.z * sc; o.w += ov.w * sc;
        }
        ushort4 res;
        if (M <= -1e9f + 1e-6f) {
            res.x = vg[(size_t)(cb + 0) * 1024];
            res.y = vg[(size_t)(cb + 1) * 1024];
            res.z = vg[(size_t)(cb + 2) * 1024];
            res.w = vg[(size_t)(cb + 3) * 1024];
        } else {
            const float inv = 1.f / L;
            res.x = f2bf(o.x * inv); res.y = f2bf(o.y * inv);
            res.z = f2bf(o.z * inv); res.w = f2bf(o.w * inv);
        }
        *(ushort4*)&aout[((size_t)(b * 1024 + i0 + r)) * 512 + h * 64 + cb] = res;
    }
}

// ============================================================
extern "C" void kernel_launch(void* const* d_in, const int* in_sizes, int n_in,
                              void* d_out, int out_size, void* d_ws, size_t ws_size,
                              hipStream_t stream) {
    const float* x     = (const float*)d_in[0];
    const int*   mask  = (const int*)d_in[1];
    const float* Wqkv  = (const float*)d_in[2];
    const float* Wproj = (const float*)d_in[3];
    const float* bproj = (const float*)d_in[4];
    const float* Wsel1 = (const float*)d_in[5];
    const float* bsel1 = (const float*)d_in[6];
    const float* Wsel2 = (const float*)d_in[7];
    const float* bsel2 = (const float*)d_in[8];
    const float* ltau  = (const float*)d_in[9];
    const float* sw    = (const float*)d_in[10];
    const float* sb    = (const float*)d_in[11];
    char* ws = (char*)d_ws;
    unsigned short* xb     = (unsigned short*)(ws + OFF_XB);
    unsigned short* wqkvb  = (unsigned short*)(ws + OFF_WQKV);
    unsigned short* wprojb = (unsigned short*)(ws + OFF_WPROJ);
    unsigned short* q      = (unsigned short*)(ws + OFF_Q);
    unsigned short* k      = (unsigned short*)(ws + OFF_K);
    unsigned short* vT     = (unsigned short*)(ws + OFF_VT);
    unsigned short* attnb  = (unsigned short*)(ws + OFF_AT);
    float* pw  = (float*)(ws + OFF_PW);
    float* par = (float*)(ws + OFF_PAR);
    float* out = (float*)d_out;
    (void)in_sizes; (void)n_in; (void)out_size; (void)ws_size;

    cvt_pool_x<<<dim3(4, 64), 256, 0, stream>>>(x, xb, par);
    cvt_w<<<1024, 256, 0, stream>>>(Wqkv, Wproj, wqkvb, wprojb);
    selector_kernel<<<4, 256, 0, stream>>>(par, Wsel1, bsel1, Wsel2, bsel2, ltau, pw);
    gemm_qkv<<<dim3(12, 32), 256, 0, stream>>>(xb, wqkvb, q, k, vT);
    attn_mfma<<<2048, 256, 0, stream>>>(q, k, vT, mask, pw, sw, sb, attnb);
    gemm_proj<<<dim3(4, 64), 256, 0, stream>>>(attnb, wprojb, bproj, out);
}

// Round 5
// 200.095 us; speedup vs baseline: 3.4875x; 1.0965x over previous
//
#include <hip/hip_runtime.h>
#include <math.h>

typedef __attribute__((ext_vector_type(8))) short short8;
typedef __attribute__((ext_vector_type(4))) float floatx4;

#define MFMA16(a, b, c) __builtin_amdgcn_mfma_f32_16x16x32_bf16(a, b, c, 0, 0, 0)

// ---- fixed sizes: B=4 L=1024 D=512 H=8 HD=64 HID=256 half-win=16 KK=716 scale=1/8 ----

// ---- workspace byte offsets ----
#define OFF_XB    ((size_t)0)          // x bf16 [4096][512]
#define OFF_WQKV  ((size_t)4194304)    // Wqkv bf16 [1536][512]
#define OFF_WPROJ ((size_t)5767168)    // Wproj bf16 [512][512]
#define OFF_Q     ((size_t)6291456)    // q bf16 [32][1024][64] (scale folded)
#define OFF_K     ((size_t)10485760)   // k bf16 [32][1024][64]
#define OFF_VT    ((size_t)14680064)   // vT bf16 [32][64][1024]
#define OFF_AT    ((size_t)18874368)   // attn out bf16 [4096][512]
#define OFF_PW    ((size_t)23068672)   // pw fp32 [4][3]
#define OFF_PAR   ((size_t)23069696)   // pool partials fp32 [4][64][512]

__device__ __forceinline__ unsigned short f2bf(float f) {  // RNE
    unsigned u = __float_as_uint(f);
    return (unsigned short)((u + 0x7fffu + ((u >> 16) & 1u)) >> 16);
}
__device__ __forceinline__ float bf2f(unsigned short s) {
    return __uint_as_float((unsigned)s << 16);
}
// async global->LDS, 16B/lane; LDS dest = wave-uniform base + lane*16 (m104)
__device__ __forceinline__ void gl16(const void* g, void* l) {
    __builtin_amdgcn_global_load_lds(
        (const __attribute__((address_space(1))) unsigned*)g,
        (__attribute__((address_space(3))) unsigned*)l, 16, 0, 0);
}

// ============================================================
// All conversions + pooling in one launch. grid 1280, block 256.
// blocks 0..255: x->bf16 + pool partials (b=bid>>6, lb=bid&63, 16 rows each)
// blocks 256..1279: Wqkv/Wproj -> bf16 (float4 granules)
// ============================================================
__global__ __launch_bounds__(256)
void cvt_all(const float* __restrict__ x, const float* __restrict__ wqkv,
             const float* __restrict__ wproj, unsigned short* __restrict__ xb,
             unsigned short* __restrict__ oq, unsigned short* __restrict__ op,
             float* __restrict__ partial)
{
    const int bid = blockIdx.x, t = threadIdx.x;
    if (bid < 256) {
        const int b = bid >> 6, lb = bid & 63;
        const size_t base = ((size_t)b * 1024 + lb * 16) * 512;
        float s0 = 0.f, s1 = 0.f;
        #pragma unroll 4
        for (int l = 0; l < 16; ++l) {
            float v0 = x[base + (size_t)l * 512 + t];
            float v1 = x[base + (size_t)l * 512 + t + 256];
            s0 += v0; s1 += v1;
            xb[base + (size_t)l * 512 + t] = f2bf(v0);
            xb[base + (size_t)l * 512 + t + 256] = f2bf(v1);
        }
        partial[((size_t)b * 64 + lb) * 512 + t] = s0;
        partial[((size_t)b * 64 + lb) * 512 + t + 256] = s1;
    } else {
        const int i = (bid - 256) * 256 + t;
        if (i < 196608) {
            float4 f = ((const float4*)wqkv)[i];
            ((ushort4*)oq)[i] = make_ushort4(f2bf(f.x), f2bf(f.y), f2bf(f.z), f2bf(f.w));
        } else {
            const int j = i - 196608;   // < 65536
            float4 f = ((const float4*)wproj)[j];
            ((ushort4*)op)[j] = make_ushort4(f2bf(f.x), f2bf(f.y), f2bf(f.z), f2bf(f.w));
        }
    }
}

// ============================================================
__global__ __launch_bounds__(256)
void selector_kernel(const float* __restrict__ partial,
                     const float* __restrict__ W1, const float* __restrict__ b1,
                     const float* __restrict__ W2, const float* __restrict__ b2,
                     const float* __restrict__ ltau, float* __restrict__ pwout)
{
    __shared__ float pooled[512];
    __shared__ float h1[256];
    __shared__ float lg[3];
    const int b = blockIdx.x, t = threadIdx.x;
    float s0 = 0.f, s1 = 0.f;
    for (int p = 0; p < 64; ++p) {
        s0 += partial[((size_t)b * 64 + p) * 512 + t];
        s1 += partial[((size_t)b * 64 + p) * 512 + t + 256];
    }
    pooled[t]       = s0 * (1.f / 1024.f);
    pooled[t + 256] = s1 * (1.f / 1024.f);
    __syncthreads();
    float acc = b1[t];
    const float* w1 = W1 + (size_t)t * 512;
    for (int d = 0; d < 512; d += 4) {
        float4 w4 = *(const float4*)(w1 + d);
        acc += w4.x * pooled[d] + w4.y * pooled[d + 1] + w4.z * pooled[d + 2] + w4.w * pooled[d + 3];
    }
    h1[t] = fmaxf(acc, 0.f);
    __syncthreads();
    if (t < 3) {
        float a = b2[t];
        const float* w2 = W2 + t * 256;
        for (int i = 0; i < 256; ++i) a += w2[i] * h1[i];
        float tauv = fminf(fmaxf(expf(ltau[0]), 1e-4f), 10.f);
        lg[t] = a / tauv;
    }
    __syncthreads();
    if (t == 0) {
        float m = fmaxf(lg[0], fmaxf(lg[1], lg[2]));
        float e0 = expf(lg[0] - m), e1 = expf(lg[1] - m), e2 = expf(lg[2] - m);
        float inv = 1.f / (e0 + e1 + e2);
        pwout[b * 3 + 0] = e0 * inv;
        pwout[b * 3 + 1] = e1 * inv;
        pwout[b * 3 + 2] = e2 * inv;
    }
}

// ============================================================
// QKV GEMM, m97-style: global_load_lds(16B) staging, BK=32, 2-barrier K-loop.
// Tile 256m x 64n, grid (24,16): bx -> (which,head), by -> m0=by*256.
// XCD affinity: linear id % 8 == bx % 8 == head % 8 == g % 8, matching attn's
// reader blocks -> q/k/vT stay in the local XCD L2.
// Epilogue: LDS-transposed coalesced stores (tile overlays staging region).
// ============================================================
__global__ __launch_bounds__(256)
void gemm_qkv(const unsigned short* __restrict__ xb, const unsigned short* __restrict__ wb,
              unsigned short* __restrict__ qo, unsigned short* __restrict__ ko,
              unsigned short* __restrict__ vTo)
{
    __shared__ __align__(16) char smem[36864];      // staging 20KB / epilogue tiles 36.9KB
    unsigned short* As = (unsigned short*)smem;            // [256][32] bf16, 16KB
    unsigned short* Bs = (unsigned short*)(smem + 16384);  // [64][32] bf16, 4KB

    const int t = threadIdx.x;
    const int w = t >> 6, l64 = t & 63;
    const int ln = l64 & 15, quad = l64 >> 4;
    const int bx = blockIdx.x;           // 0..23
    const int m0 = blockIdx.y << 8;      // 0..3840
    const int nb = bx << 6;
    const int arow = l64 >> 2, akq = l64 & 3;   // staging lane map (16 rows x 64B per inst)

    floatx4 acc[4][4];
    #pragma unroll
    for (int i = 0; i < 4; ++i)
        #pragma unroll
        for (int j = 0; j < 4; ++j) acc[i][j] = (floatx4){0.f, 0.f, 0.f, 0.f};

    for (int s = 0; s < 16; ++s) {
        const int k0 = s * 32;
        #pragma unroll
        for (int ii = 0; ii < 4; ++ii) {
            const int it = w * 4 + ii;
            gl16(xb + (size_t)(m0 + it * 16 + arow) * 512 + k0 + akq * 8,
                 (char*)As + it * 1024);
        }
        gl16(wb + (size_t)(nb + w * 16 + arow) * 512 + k0 + akq * 8,
             (char*)Bs + w * 1024);
        __syncthreads();
        short8 af[4], bf[4];
        #pragma unroll
        for (int i = 0; i < 4; ++i)
            af[i] = *(const short8*)((const char*)As + (w * 64 + i * 16 + ln) * 64 + quad * 16);
        #pragma unroll
        for (int j = 0; j < 4; ++j)
            bf[j] = *(const short8*)((const char*)Bs + (j * 16 + ln) * 64 + quad * 16);
        #pragma unroll
        for (int i = 0; i < 4; ++i)
            #pragma unroll
            for (int j = 0; j < 4; ++j)
                acc[i][j] = MFMA16(af[i], bf[j], acc[i][j]);
        __syncthreads();
    }

    // ---- epilogue: wave-private LDS transpose -> coalesced ushort4 stores ----
    unsigned short* tw = (unsigned short*)(smem + w * 9216);   // [64][72]
    const int which = bx >> 3, hh = bx & 7;
    const int bb = blockIdx.y >> 2;
    const int g = bb * 8 + hh;
    const int ll0 = (m0 & 1023) + w * 64;

    if (which == 2) {
        #pragma unroll
        for (int j = 0; j < 4; ++j)
            #pragma unroll
            for (int i = 0; i < 4; ++i)
                #pragma unroll
                for (int reg = 0; reg < 4; ++reg)
                    tw[(j * 16 + ln) * 72 + i * 16 + quad * 4 + reg] = f2bf(acc[i][j][reg]);
        unsigned short* dst = vTo + (size_t)g * 64 * 1024 + ll0;
        #pragma unroll
        for (int it = 0; it < 16; ++it) {
            const int e = it * 4 + quad;
            *(ushort4*)(dst + (size_t)e * 1024 + ln * 4) = *(const ushort4*)&tw[e * 72 + ln * 4];
        }
    } else {
        const float sc = (which == 0) ? 0.125f : 1.f;   // fold q scale (pow2, exact)
        #pragma unroll
        for (int j = 0; j < 4; ++j)
            #pragma unroll
            for (int i = 0; i < 4; ++i)
                #pragma unroll
                for (int reg = 0; reg < 4; ++reg)
                    tw[(i * 16 + quad * 4 + reg) * 72 + j * 16 + ln] = f2bf(acc[i][j][reg] * sc);
        unsigned short* dst = (which == 0 ? qo : ko) + ((size_t)g * 1024 + ll0) * 64;
        #pragma unroll
        for (int it = 0; it < 16; ++it) {
            const int m = it * 4 + quad;
            *(ushort4*)(dst + (size_t)m * 64 + ln * 4) = *(const ushort4*)&tw[m * 72 + ln * 4];
        }
    }
}

// ============================================================
// Proj GEMM, LDS-staged: tile 128m x 64n, BK=32, grid (8,32).
// fp32 output + bias, natural C-layout stores.
// ============================================================
__global__ __launch_bounds__(256)
void gemm_proj(const unsigned short* __restrict__ ab, const unsigned short* __restrict__ wb,
               const float* __restrict__ bias, float* __restrict__ out)
{
    __shared__ __align__(16) unsigned short As[128 * 32];
    __shared__ __align__(16) unsigned short Bs[64 * 32];
    const int t = threadIdx.x;
    const int w = t >> 6, l64 = t & 63;
    const int ln = l64 & 15, quad = l64 >> 4;
    const int nb = blockIdx.x << 6;
    const int m0 = blockIdx.y << 7;
    const int arow = l64 >> 2, akq = l64 & 3;

    floatx4 acc[2][4];
    #pragma unroll
    for (int i = 0; i < 2; ++i)
        #pragma unroll
        for (int j = 0; j < 4; ++j) acc[i][j] = (floatx4){0.f, 0.f, 0.f, 0.f};

    for (int s = 0; s < 16; ++s) {
        const int k0 = s * 32;
        #pragma unroll
        for (int ii = 0; ii < 2; ++ii) {
            const int it = w * 2 + ii;
            gl16(ab + (size_t)(m0 + it * 16 + arow) * 512 + k0 + akq * 8,
                 (char*)As + it * 1024);
        }
        gl16(wb + (size_t)(nb + w * 16 + arow) * 512 + k0 + akq * 8,
             (char*)Bs + w * 1024);
        __syncthreads();
        short8 af[2], bf[4];
        #pragma unroll
        for (int i = 0; i < 2; ++i)
            af[i] = *(const short8*)((const char*)As + (w * 32 + i * 16 + ln) * 64 + quad * 16);
        #pragma unroll
        for (int j = 0; j < 4; ++j)
            bf[j] = *(const short8*)((const char*)Bs + (j * 16 + ln) * 64 + quad * 16);
        #pragma unroll
        for (int i = 0; i < 2; ++i)
            #pragma unroll
            for (int j = 0; j < 4; ++j)
                acc[i][j] = MFMA16(af[i], bf[j], acc[i][j]);
        __syncthreads();
    }
    #pragma unroll
    for (int j = 0; j < 4; ++j) {
        const float bv = bias[nb + j * 16 + ln];
        #pragma unroll
        for (int i = 0; i < 2; ++i)
            #pragma unroll
            for (int reg = 0; reg < 4; ++reg)
                out[(size_t)(m0 + w * 32 + i * 16 + quad * 4 + reg) * 512 + nb + j * 16 + ln] =
                    acc[i][j][reg] + bv;
    }
}

// ============================================================
// Fused attention. block = 16 Q-rows; 4 waves x 2 key-chunks of 128; LDS merge.
// grid 2048 (id%8 == g%8 -> reads the XCD-local q/k/vT gemm_qkv just wrote).
// K-prefetch recycling: chunk-1's 16 K-loads issue right after chunk-0's QK
// MFMAs consume the registers -> K latency hidden under softmax+PV.
// ============================================================
__global__ __launch_bounds__(256)
void attn_mfma(const unsigned short* __restrict__ qm, const unsigned short* __restrict__ km,
               const unsigned short* __restrict__ vT, const int* __restrict__ mask,
               const float* __restrict__ pw, const float* __restrict__ sw,
               const float* __restrict__ sb, unsigned short* __restrict__ aout)
{
    __shared__ int mk[1024];
    __shared__ float PO[4][16][68];   // per-wave union: P bf16[16][136] / radix ubuf / Opart
    __shared__ float msh[4][16], lsh[4][16];
    __shared__ unsigned kths[4][16];

    const int t = threadIdx.x;
    const int w = t >> 6, l64 = t & 63;
    const int ln = l64 & 15, quad = l64 >> 4;
    const int g = blockIdx.x & 31;
    const int rt = blockIdx.x >> 5;
    const int b = g >> 3, h = g & 7;
    const int i0 = rt * 16;

    const unsigned short* qg = qm + (size_t)g * 1024 * 64;
    const unsigned short* kg = km + (size_t)g * 1024 * 64;
    const unsigned short* vg = vT + (size_t)g * 64 * 1024;

    *(int4*)&mk[t * 4] = *(const int4*)(mask + b * 1024 + t * 4);

    const float pw0 = pw[b * 3 + 0], pw1 = pw[b * 3 + 1], pw2 = pw[b * 3 + 2];
    const bool a00 = pw1 > 0.05f;
    const bool a10 = (pw0 * 1.0f + pw1) > 0.05f;
    const bool a01 = (pw1 + pw2) > 0.05f;
    const bool a11 = ((pw0 * 1.0f + pw1) + pw2) > 0.05f;
    const bool need_sparse = (!a00 && a01) || (!a10 && a11);
    const bool flat_ok = (!need_sparse) && a00 && a10;  // allowed==true iff mk!=0, exactly
    const float w_h = sw[h], b_h = sb[h];
    __syncthreads();

    // ---- rare path: exact per-row kth (k=716), bitwise radix select ----
    unsigned kth_r[4] = {0u, 0u, 0u, 0u};
    if (need_sparse) {
        unsigned* ub = (unsigned*)&PO[w][0][0];
        for (int r = 0; r < 16; ++r) {
            const unsigned short* qr = qg + (size_t)(i0 + r) * 64;
            for (int c = 0; c < 16; ++c) {
                const int col = c * 64 + l64;
                const unsigned short* kr = kg + (size_t)col * 64;
                float s = 0.f;
                for (int e = 0; e < 64; ++e) s += bf2f(qr[e]) * bf2f(kr[e]);
                unsigned uu = __float_as_uint(s * w_h + b_h);
                ub[col] = (uu & 0x80000000u) ? ~uu : (uu | 0x80000000u);
            }
            unsigned u[16];
            #pragma unroll
            for (int c = 0; c < 16; ++c) u[c] = ub[l64 + c * 64];
            unsigned act = 0xFFFFu, p = 0u;
            int kk = 716;
            for (int bit = 31; bit >= 0; --bit) {
                unsigned ones = 0u;
                #pragma unroll
                for (int c = 0; c < 16; ++c)
                    if (((act >> c) & 1u) && ((u[c] >> bit) & 1u)) ones |= (1u << c);
                int c1 = __popc(ones);
                for (int off = 32; off; off >>= 1) c1 += __shfl_xor(c1, off);
                if (kk <= c1) { p |= (1u << bit); act &= ones; }
                else          { kk -= c1; act &= ~ones; }
            }
            if (l64 == 0) kths[w][r] = p;
        }
        #pragma unroll
        for (int reg = 0; reg < 4; ++reg) kth_r[reg] = kths[w][quad * 4 + reg];
    }

    // ---- Q A-fragments (rows i0..i0+15, same for all waves) ----
    const unsigned short* qrow = qg + (size_t)(i0 + ln) * 64 + quad * 8;
    const short8 aq0 = *(const short8*)qrow;
    const short8 aq1 = *(const short8*)(qrow + 32);

    float m_r[4] = {-3e38f, -3e38f, -3e38f, -3e38f};
    float l_r[4] = {0.f, 0.f, 0.f, 0.f};
    floatx4 accv[4];
    #pragma unroll
    for (int et = 0; et < 4; ++et) accv[et] = (floatx4){0.f, 0.f, 0.f, 0.f};
    unsigned short* Pw = (unsigned short*)&PO[w][0][0];   // stride 136 shorts

    // preload chunk-0 K fragments (16 loads in flight)
    const int j0a = (w * 2) << 7;
    const unsigned short* kb_base = kg + (size_t)(j0a + ln) * 64 + quad * 8;
    short8 kb0[8], kb1[8];
    #pragma unroll
    for (int nt = 0; nt < 8; ++nt) {
        kb0[nt] = *(const short8*)(kb_base + (size_t)nt * 1024);
        kb1[nt] = *(const short8*)(kb_base + (size_t)nt * 1024 + 32);
    }

    #pragma unroll
    for (int cc = 0; cc < 2; ++cc) {
        const int j0 = (w * 2 + cc) << 7;
        const bool mall = __all((mk[j0 + l64] != 0) && (mk[j0 + 64 + l64] != 0));
        const bool fast = flat_ok && mall;

        // V prefetch for et=0
        short8 vb_cur[4], vb_nxt[4];
        #pragma unroll
        for (int ks = 0; ks < 4; ++ks)
            vb_cur[ks] = *(const short8*)(vg + (size_t)ln * 1024 + j0 + ks * 32 + quad * 8);

        // ---- QK^T: 16 rows x 128 keys ----
        floatx4 sfr[8];
        #pragma unroll
        for (int nt = 0; nt < 8; ++nt) {
            floatx4 z = (floatx4){0.f, 0.f, 0.f, 0.f};
            z = MFMA16(aq0, kb0[nt], z);
            z = MFMA16(aq1, kb1[nt], z);
            sfr[nt] = z;
        }
        // recycle kb registers: issue chunk-1's K loads now (hidden under softmax+PV)
        if (cc == 0) {
            const unsigned short* kn = kb_base + 128 * 64;
            #pragma unroll
            for (int nt = 0; nt < 8; ++nt) {
                kb0[nt] = *(const short8*)(kn + (size_t)nt * 1024);
                kb1[nt] = *(const short8*)(kn + (size_t)nt * 1024 + 32);
            }
        }

        // ---- masking + row max ----
        float rm[4] = {-3e38f, -3e38f, -3e38f, -3e38f};
        if (fast) {
            #pragma unroll
            for (int nt = 0; nt < 8; ++nt)
                #pragma unroll
                for (int reg = 0; reg < 4; ++reg) rm[reg] = fmaxf(rm[reg], sfr[nt][reg]);
        } else {
            #pragma unroll
            for (int nt = 0; nt < 8; ++nt) {
                const int j = j0 + nt * 16 + ln;
                const bool mk0 = (mk[j] == 0);
                #pragma unroll
                for (int reg = 0; reg < 4; ++reg) {
                    const int i = i0 + quad * 4 + reg;
                    const float s = sfr[nt][reg];
                    const bool loc = (j >= i - 16) && (j <= i + 16);
                    bool sm = false;
                    if (need_sparse) {
                        unsigned uu = __float_as_uint(s * w_h + b_h);
                        unsigned key = (uu & 0x80000000u) ? ~uu : (uu | 0x80000000u);
                        sm = key >= kth_r[reg];
                    }
                    bool allowed = loc ? (sm ? a11 : a10) : (sm ? a01 : a00);
                    if (mk0) allowed = false;
                    const float se = allowed ? s : -1e9f;
                    sfr[nt][reg] = se;
                    rm[reg] = fmaxf(rm[reg], se);
                }
            }
        }
        #pragma unroll
        for (int reg = 0; reg < 4; ++reg) {
            float v = rm[reg];
            v = fmaxf(v, __shfl_xor(v, 1));
            v = fmaxf(v, __shfl_xor(v, 2));
            v = fmaxf(v, __shfl_xor(v, 4));
            v = fmaxf(v, __shfl_xor(v, 8));
            rm[reg] = v;
        }
        float alpha[4], rs[4];
        #pragma unroll
        for (int reg = 0; reg < 4; ++reg) {
            const float mn = fmaxf(m_r[reg], rm[reg]);
            alpha[reg] = __expf(m_r[reg] - mn);
            m_r[reg] = mn;
            rs[reg] = 0.f;
        }
        // ---- P = exp(s-m) -> bf16 -> wave-private LDS (C->A transpose) ----
        #pragma unroll
        for (int nt = 0; nt < 8; ++nt)
            #pragma unroll
            for (int reg = 0; reg < 4; ++reg) {
                const float p = __expf(sfr[nt][reg] - m_r[reg]);
                rs[reg] += p;
                Pw[(quad * 4 + reg) * 136 + nt * 16 + ln] = f2bf(p);
            }
        #pragma unroll
        for (int reg = 0; reg < 4; ++reg) {
            float v = rs[reg];
            v += __shfl_xor(v, 1);
            v += __shfl_xor(v, 2);
            v += __shfl_xor(v, 4);
            v += __shfl_xor(v, 8);
            l_r[reg] = l_r[reg] * alpha[reg] + v;
        }
        short8 pa[4];
        #pragma unroll
        for (int ks = 0; ks < 4; ++ks)
            pa[ks] = *(const short8*)&Pw[ln * 136 + ks * 32 + quad * 8];
        // ---- PV with et-pipelined V fragment loads ----
        #pragma unroll
        for (int et = 0; et < 4; ++et) {
            if (et < 3) {
                #pragma unroll
                for (int ks = 0; ks < 4; ++ks)
                    vb_nxt[ks] = *(const short8*)(vg + (size_t)((et + 1) * 16 + ln) * 1024 +
                                                  j0 + ks * 32 + quad * 8);
            }
            floatx4 a = accv[et];
            a[0] *= alpha[0]; a[1] *= alpha[1]; a[2] *= alpha[2]; a[3] *= alpha[3];
            #pragma unroll
            for (int ks = 0; ks < 4; ++ks) a = MFMA16(pa[ks], vb_cur[ks], a);
            accv[et] = a;
            #pragma unroll
            for (int ks = 0; ks < 4; ++ks) vb_cur[ks] = vb_nxt[ks];
        }
    }

    // ---- per-wave partials into the (now-free) P region ----
    #pragma unroll
    for (int et = 0; et < 4; ++et)
        #pragma unroll
        for (int reg = 0; reg < 4; ++reg)
            PO[w][quad * 4 + reg][et * 16 + ln] = accv[et][reg];
    if (ln == 0) {
        #pragma unroll
        for (int reg = 0; reg < 4; ++reg) {
            msh[w][quad * 4 + reg] = m_r[reg];
            lsh[w][quad * 4 + reg] = l_r[reg];
        }
    }
    __syncthreads();

    // ---- merge 4 wave-partials -> final output ----
    {
        const int r = t >> 4, cb = (t & 15) * 4;
        float M = fmaxf(fmaxf(msh[0][r], msh[1][r]), fmaxf(msh[2][r], msh[3][r]));
        float L = 0.f;
        float4 o = make_float4(0.f, 0.f, 0.f, 0.f);
        #pragma unroll
        for (int wv = 0; wv < 4; ++wv) {
            const float sc = __expf(msh[wv][r] - M);
            L += lsh[wv][r] * sc;
            float4 ov = *(const float4*)&PO[wv][r][cb];
            o.x += ov.x * sc; o.y += ov.y * sc; o.z += ov.z * sc; o.w += ov.w * sc;
        }
        ushort4 res;
        if (M <= -1e9f + 1e-6f) {
            res.x = vg[(size_t)(cb + 0) * 1024];
            res.y = vg[(size_t)(cb + 1) * 1024];
            res.z = vg[(size_t)(cb + 2) * 1024];
            res.w = vg[(size_t)(cb + 3) * 1024];
        } else {
            const float inv = 1.f / L;
            res.x = f2bf(o.x * inv); res.y = f2bf(o.y * inv);
            res.z = f2bf(o.z * inv); res.w = f2bf(o.w * inv);
        }
        *(ushort4*)&aout[((size_t)(b * 1024 + i0 + r)) * 512 + h * 64 + cb] = res;
    }
}

// ============================================================
extern "C" void kernel_launch(void* const* d_in, const int* in_sizes, int n_in,
                              void* d_out, int out_size, void* d_ws, size_t ws_size,
                              hipStream_t stream) {
    const float* x     = (const float*)d_in[0];
    const int*   mask  = (const int*)d_in[1];
    const float* Wqkv  = (const float*)d_in[2];
    const float* Wproj = (const float*)d_in[3];
    const float* bproj = (const float*)d_in[4];
    const float* Wsel1 = (const float*)d_in[5];
    const float* bsel1 = (const float*)d_in[6];
    const float* Wsel2 = (const float*)d_in[7];
    const float* bsel2 = (const float*)d_in[8];
    const float* ltau  = (const float*)d_in[9];
    const float* sw    = (const float*)d_in[10];
    const float* sb    = (const float*)d_in[11];
    char* ws = (char*)d_ws;
    unsigned short* xb     = (unsigned short*)(ws + OFF_XB);
    unsigned short* wqkvb  = (unsigned short*)(ws + OFF_WQKV);
    unsigned short* wprojb = (unsigned short*)(ws + OFF_WPROJ);
    unsigned short* q      = (unsigned short*)(ws + OFF_Q);
    unsigned short* k      = (unsigned short*)(ws + OFF_K);
    unsigned short* vT     = (unsigned short*)(ws + OFF_VT);
    unsigned short* attnb  = (unsigned short*)(ws + OFF_AT);
    float* pw  = (float*)(ws + OFF_PW);
    float* par = (float*)(ws + OFF_PAR);
    float* out = (float*)d_out;
    (void)in_sizes; (void)n_in; (void)out_size; (void)ws_size;

    cvt_all<<<1280, 256, 0, stream>>>(x, Wqkv, Wproj, xb, wqkvb, wprojb, par);
    selector_kernel<<<4, 256, 0, stream>>>(par, Wsel1, bsel1, Wsel2, bsel2, ltau, pw);
    gemm_qkv<<<dim3(24, 16), 256, 0, stream>>>(xb, wqkvb, q, k, vT);
    attn_mfma<<<2048, 256, 0, stream>>>(q, k, vT, mask, pw, sw, sb, attnb);
    gemm_proj<<<dim3(8, 32), 256, 0, stream>>>(attnb, wprojb, bproj, out);
}

// Round 6
// 163.832 us; speedup vs baseline: 4.2594x; 1.2213x over previous
//
#include <hip/hip_runtime.h>
#include <math.h>

typedef __attribute__((ext_vector_type(8))) short short8;
typedef __attribute__((ext_vector_type(4))) float floatx4;

#define MFMA16(a, b, c) __builtin_amdgcn_mfma_f32_16x16x32_bf16(a, b, c, 0, 0, 0)

// ---- fixed sizes: B=4 L=1024 D=512 H=8 HD=64 HID=256 half-win=16 KK=716 scale=1/8 ----
//
// FRAGMENT-ORDER LAYOUTS (this round's change): every staged tensor is stored as
// 512-short (1KB) MFMA-fragment blocks where lane l64's 8 shorts sit at base+l64*8.
//  - 512-deep (x, Wqkv, Wproj, attn-out):  FRAG512(row,k) tile-stride 8192
//  - 64-deep  (q, k):                      FRAGQK(row,e)  tile-stride 1024
//  - v (per 128-key chunk):                FRAGV(key,e)   chunk-stride 8192
// All attn/gemm global fragment loads and all gl16 LDS images are then
// contiguous 1KB per wave-instruction: full-line coalescing + conflict-free LDS.

#define FRAG512(row, k) (((size_t)((row) >> 4)) * 8192 + (((k) >> 5) * 512) + \
                         ((((k) >> 3) & 3) * 128) + (((row) & 15) * 8) + ((k) & 7))
#define FRAGQK(row, e)  (((size_t)((row) >> 4)) * 1024 + (((e) >> 5) * 512) + \
                         ((((e) >> 3) & 3) * 128) + (((row) & 15) * 8) + ((e) & 7))
#define FRAGV(key, e)   (((size_t)((key) >> 7)) * 8192 + \
                         ((((e) >> 4) * 4 + (((key) & 127) >> 5)) * 512) + \
                         (((((key) & 31) >> 3) * 16 + ((e) & 15)) * 8) + ((key) & 7))

// ---- workspace byte offsets ----
#define OFF_XB    ((size_t)0)          // x bf16 frag [4096][512]
#define OFF_WQKV  ((size_t)4194304)    // Wqkv bf16 frag [1536][512]
#define OFF_WPROJ ((size_t)5767168)    // Wproj bf16 frag [512][512]
#define OFF_Q     ((size_t)6291456)    // q bf16 frag [32][1024][64] (scale folded)
#define OFF_K     ((size_t)10485760)   // k bf16 frag [32][1024][64]
#define OFF_VT    ((size_t)14680064)   // v bf16 frag [32] chunks
#define OFF_AT    ((size_t)18874368)   // attn out bf16 frag [4096][512]
#define OFF_PW    ((size_t)23068672)   // pw fp32 [4][3]
#define OFF_PAR   ((size_t)23069696)   // pool partials fp32 [4][64][512]

__device__ __forceinline__ unsigned short f2bf(float f) {  // RNE
    unsigned u = __float_as_uint(f);
    return (unsigned short)((u + 0x7fffu + ((u >> 16) & 1u)) >> 16);
}
__device__ __forceinline__ float bf2f(unsigned short s) {
    return __uint_as_float((unsigned)s << 16);
}
// async global->LDS, 16B/lane; LDS dest = wave-uniform base + lane*16 (m104)
__device__ __forceinline__ void gl16(const void* g, void* l) {
    __builtin_amdgcn_global_load_lds(
        (const __attribute__((address_space(1))) unsigned*)g,
        (__attribute__((address_space(3))) unsigned*)l, 16, 0, 0);
}

// ============================================================
// fp32 [16][512] row-major tile -> bf16 fragment-order tile (8192 shorts).
// 256 threads; thread t handles (ln = t&15, quad = (t>>4)&3, kh = t>>6).
// ============================================================
__device__ __forceinline__ void frag_cvt_tile(const float* __restrict__ src,
                                              unsigned short* __restrict__ dst,
                                              const int t, const float sc)
{
    const int ln = t & 15, quad = (t >> 4) & 3, kh = t >> 6;
    #pragma unroll
    for (int i = 0; i < 4; ++i) {
        const int kb = kh + i * 4;                 // 0..15
        const float* s = src + (size_t)ln * 512 + kb * 32 + quad * 8;
        float4 f0 = *(const float4*)s;
        float4 f1 = *(const float4*)(s + 4);
        unsigned short o[8] = { f2bf(f0.x * sc), f2bf(f0.y * sc), f2bf(f0.z * sc), f2bf(f0.w * sc),
                                f2bf(f1.x * sc), f2bf(f1.y * sc), f2bf(f1.z * sc), f2bf(f1.w * sc) };
        unsigned short* d = dst + kb * 512 + (size_t)(t & 63) * 8;
        *(ushort4*)d       = make_ushort4(o[0], o[1], o[2], o[3]);
        *(ushort4*)(d + 4) = make_ushort4(o[4], o[5], o[6], o[7]);
    }
}

// ============================================================
// grid 640: [0,256) pooling partials; [256,512) x->frag; [512,640) weights->frag
// ============================================================
__global__ __launch_bounds__(256)
void cvt_all(const float* __restrict__ x, const float* __restrict__ wqkv,
             const float* __restrict__ wproj, unsigned short* __restrict__ xb,
             unsigned short* __restrict__ oq, unsigned short* __restrict__ op,
             float* __restrict__ partial)
{
    const int bid = blockIdx.x, t = threadIdx.x;
    if (bid < 256) {
        const int b = bid >> 6, lb = bid & 63;
        const size_t base = ((size_t)b * 1024 + lb * 16) * 512;
        float s0 = 0.f, s1 = 0.f;
        #pragma unroll 4
        for (int l = 0; l < 16; ++l) {
            s0 += x[base + (size_t)l * 512 + t];
            s1 += x[base + (size_t)l * 512 + t + 256];
        }
        partial[((size_t)b * 64 + lb) * 512 + t] = s0;
        partial[((size_t)b * 64 + lb) * 512 + t + 256] = s1;
    } else if (bid < 512) {
        const int rt = bid - 256;                  // 0..255
        frag_cvt_tile(x + (size_t)rt * 16 * 512, xb + (size_t)rt * 8192, t, 1.f);
    } else {
        const int tile = bid - 512;                // 0..127
        if (tile < 96)
            frag_cvt_tile(wqkv + (size_t)tile * 16 * 512, oq + (size_t)tile * 8192, t, 1.f);
        else
            frag_cvt_tile(wproj + (size_t)(tile - 96) * 16 * 512,
                          op + (size_t)(tile - 96) * 8192, t, 1.f);
    }
}

// ============================================================
__global__ __launch_bounds__(256)
void selector_kernel(const float* __restrict__ partial,
                     const float* __restrict__ W1, const float* __restrict__ b1,
                     const float* __restrict__ W2, const float* __restrict__ b2,
                     const float* __restrict__ ltau, float* __restrict__ pwout)
{
    __shared__ float pooled[512];
    __shared__ float h1[256];
    __shared__ float lg[3];
    const int b = blockIdx.x, t = threadIdx.x;
    float s0 = 0.f, s1 = 0.f;
    for (int p = 0; p < 64; ++p) {
        s0 += partial[((size_t)b * 64 + p) * 512 + t];
        s1 += partial[((size_t)b * 64 + p) * 512 + t + 256];
    }
    pooled[t]       = s0 * (1.f / 1024.f);
    pooled[t + 256] = s1 * (1.f / 1024.f);
    __syncthreads();
    float acc = b1[t];
    const float* w1 = W1 + (size_t)t * 512;
    for (int d = 0; d < 512; d += 4) {
        float4 w4 = *(const float4*)(w1 + d);
        acc += w4.x * pooled[d] + w4.y * pooled[d + 1] + w4.z * pooled[d + 2] + w4.w * pooled[d + 3];
    }
    h1[t] = fmaxf(acc, 0.f);
    __syncthreads();
    if (t < 3) {
        float a = b2[t];
        const float* w2 = W2 + t * 256;
        for (int i = 0; i < 256; ++i) a += w2[i] * h1[i];
        float tauv = fminf(fmaxf(expf(ltau[0]), 1e-4f), 10.f);
        lg[t] = a / tauv;
    }
    __syncthreads();
    if (t == 0) {
        float m = fmaxf(lg[0], fmaxf(lg[1], lg[2]));
        float e0 = expf(lg[0] - m), e1 = expf(lg[1] - m), e2 = expf(lg[2] - m);
        float inv = 1.f / (e0 + e1 + e2);
        pwout[b * 3 + 0] = e0 * inv;
        pwout[b * 3 + 1] = e1 * inv;
        pwout[b * 3 + 2] = e2 * inv;
    }
}

// ============================================================
// QKV GEMM, m97-style: 128x128 tile, BK=32, gl16 staging of fragment blocks
// (contiguous 1KB images -> conflict-free ds_read_b128). grid (12,32).
// Epilogue: LDS transpose -> q/k/v in fragment-order global layouts.
// ============================================================
__global__ __launch_bounds__(256)
void gemm_qkv(const unsigned short* __restrict__ xb, const unsigned short* __restrict__ wb,
              unsigned short* __restrict__ qo, unsigned short* __restrict__ ko,
              unsigned short* __restrict__ vo)
{
    __shared__ __align__(16) char smem[36864];       // staging 16KB / epilogue 36.9KB
    unsigned short* As = (unsigned short*)smem;             // 8 frag blocks (128m x 32k)
    unsigned short* Bs = (unsigned short*)(smem + 8192);    // 8 frag blocks (128n x 32k)

    const int t = threadIdx.x;
    const int w = t >> 6, l64 = t & 63;
    const int ln = l64 & 15, quad = l64 >> 4;
    const int bx = blockIdx.x, by = blockIdx.y;
    const int m0 = by << 7, n0 = bx << 7;
    const int mw = (w & 1) << 6, nw = (w >> 1) << 6;

    floatx4 acc[4][4];
    #pragma unroll
    for (int i = 0; i < 4; ++i)
        #pragma unroll
        for (int j = 0; j < 4; ++j) acc[i][j] = (floatx4){0.f, 0.f, 0.f, 0.f};

    for (int s = 0; s < 16; ++s) {
        const int kb = s;                            // k0 = s*32, block col index = s
        #pragma unroll
        for (int ii = 0; ii < 2; ++ii) {
            const int bi = w * 2 + ii;
            gl16(xb + ((size_t)((m0 >> 4) + bi)) * 8192 + kb * 512 + l64 * 8,
                 (char*)As + bi * 1024);
            gl16(wb + ((size_t)((n0 >> 4) + bi)) * 8192 + kb * 512 + l64 * 8,
                 (char*)Bs + bi * 1024);
        }
        __syncthreads();
        short8 af[4], bf[4];
        #pragma unroll
        for (int i = 0; i < 4; ++i)
            af[i] = *(const short8*)((const char*)As + ((mw >> 4) + i) * 1024 + l64 * 16);
        #pragma unroll
        for (int j = 0; j < 4; ++j)
            bf[j] = *(const short8*)((const char*)Bs + ((nw >> 4) + j) * 1024 + l64 * 16);
        #pragma unroll
        for (int i = 0; i < 4; ++i)
            #pragma unroll
            for (int j = 0; j < 4; ++j)
                acc[i][j] = MFMA16(af[i], bf[j], acc[i][j]);
        __syncthreads();
    }

    // ---- epilogue: wave-private 64x64 LDS tile -> fragment-order stores ----
    unsigned short* tw = (unsigned short*)(smem + w * 9216);   // [64][72]
    const int which = bx >> 2;                    // 0=q 1=k 2=v (uniform per block)
    const int hh = ((n0 + nw) >> 6) & 7;
    const int g = (by >> 3) * 8 + hh;
    const int lrow0 = (m0 & 1023) + mw;           // 64-row range within this b

    if (which == 2) {
        // tile[e][key_local]
        #pragma unroll
        for (int j = 0; j < 4; ++j)
            #pragma unroll
            for (int i = 0; i < 4; ++i)
                #pragma unroll
                for (int reg = 0; reg < 4; ++reg)
                    tw[(j * 16 + ln) * 72 + i * 16 + quad * 4 + reg] = f2bf(acc[i][j][reg]);
        const int chunk = lrow0 >> 7;
        const int ks0 = (lrow0 & 127) >> 5;       // 0 or 2
        unsigned short* dst = vo + (size_t)g * 65536 + (size_t)chunk * 8192;
        #pragma unroll
        for (int et = 0; et < 4; ++et)
            #pragma unroll
            for (int ksl = 0; ksl < 2; ++ksl) {
                const unsigned short* srcp = &tw[(et * 16 + ln) * 72 + ksl * 32 + quad * 8];
                *(short8*)(dst + (et * 4 + ks0 + ksl) * 512 + l64 * 8) = *(const short8*)srcp;
            }
    } else {
        const float sc = (which == 0) ? 0.125f : 1.f;   // fold q scale (pow2, exact)
        // tile[row_local][e]
        #pragma unroll
        for (int j = 0; j < 4; ++j)
            #pragma unroll
            for (int i = 0; i < 4; ++i)
                #pragma unroll
                for (int reg = 0; reg < 4; ++reg)
                    tw[(i * 16 + quad * 4 + reg) * 72 + j * 16 + ln] = f2bf(acc[i][j][reg] * sc);
        unsigned short* dst = (which == 0 ? qo : ko) + (size_t)g * 65536;
        #pragma unroll
        for (int rt = 0; rt < 4; ++rt)
            #pragma unroll
            for (int eh = 0; eh < 2; ++eh) {
                const unsigned short* srcp = &tw[(rt * 16 + ln) * 72 + eh * 32 + quad * 8];
                *(short8*)(dst + ((size_t)((lrow0 >> 4) + rt)) * 1024 + eh * 512 + l64 * 8) =
                    *(const short8*)srcp;
            }
    }
}

// ============================================================
// Proj GEMM: 128m x 64n tile, BK=32, grid (8,32). A=attn frag, B=Wproj frag.
// fp32 out + bias, natural row-major stores.
// ============================================================
__global__ __launch_bounds__(256)
void gemm_proj(const unsigned short* __restrict__ ab, const unsigned short* __restrict__ wb,
               const float* __restrict__ bias, float* __restrict__ out)
{
    __shared__ __align__(16) unsigned short As[8 * 512];
    __shared__ __align__(16) unsigned short Bs[4 * 512];
    const int t = threadIdx.x;
    const int w = t >> 6, l64 = t & 63;
    const int ln = l64 & 15, quad = l64 >> 4;
    const int n0 = blockIdx.x << 6;
    const int m0 = blockIdx.y << 7;
    const int mw = (w & 1) << 6, nw = (w >> 1) << 5;

    floatx4 acc[4][2];
    #pragma unroll
    for (int i = 0; i < 4; ++i)
        #pragma unroll
        for (int j = 0; j < 2; ++j) acc[i][j] = (floatx4){0.f, 0.f, 0.f, 0.f};

    for (int s = 0; s < 16; ++s) {
        #pragma unroll
        for (int ii = 0; ii < 2; ++ii) {
            const int bi = w * 2 + ii;
            gl16(ab + ((size_t)((m0 >> 4) + bi)) * 8192 + s * 512 + l64 * 8,
                 (char*)As + bi * 1024);
        }
        gl16(wb + ((size_t)((n0 >> 4) + w)) * 8192 + s * 512 + l64 * 8,
             (char*)Bs + w * 1024);
        __syncthreads();
        short8 af[4], bf[2];
        #pragma unroll
        for (int i = 0; i < 4; ++i)
            af[i] = *(const short8*)((const char*)As + ((mw >> 4) + i) * 1024 + l64 * 16);
        #pragma unroll
        for (int j = 0; j < 2; ++j)
            bf[j] = *(const short8*)((const char*)Bs + ((nw >> 4) + j) * 1024 + l64 * 16);
        #pragma unroll
        for (int i = 0; i < 4; ++i)
            #pragma unroll
            for (int j = 0; j < 2; ++j)
                acc[i][j] = MFMA16(af[i], bf[j], acc[i][j]);
        __syncthreads();
    }
    #pragma unroll
    for (int j = 0; j < 2; ++j) {
        const float bv = bias[n0 + nw + j * 16 + ln];
        #pragma unroll
        for (int i = 0; i < 4; ++i)
            #pragma unroll
            for (int reg = 0; reg < 4; ++reg)
                out[(size_t)(m0 + mw + i * 16 + quad * 4 + reg) * 512 + n0 + nw + j * 16 + ln] =
                    acc[i][j][reg] + bv;
    }
}

// ============================================================
// Fused attention (round-4 register structure, VGPR<=128; fragment-order loads).
// block = 16 Q-rows; 4 waves x 2 key-chunks of 128; LDS merge. grid 2048.
// All K/V/Q fragment loads are contiguous 1KB wave loads (full-line coalesced).
// ============================================================
__global__ __launch_bounds__(256)
void attn_mfma(const unsigned short* __restrict__ qm, const unsigned short* __restrict__ km,
               const unsigned short* __restrict__ vm, const int* __restrict__ mask,
               const float* __restrict__ pw, const float* __restrict__ sw,
               const float* __restrict__ sb, unsigned short* __restrict__ aout)
{
    __shared__ int mk[1024];
    __shared__ float PO[4][16][68];   // per-wave union: P bf16[16][136] / radix ubuf / Opart
    __shared__ float msh[4][16], lsh[4][16];
    __shared__ unsigned kths[4][16];

    const int t = threadIdx.x;
    const int w = t >> 6, l64 = t & 63;
    const int ln = l64 & 15, quad = l64 >> 4;
    const int g = blockIdx.x & 31;
    const int rt = blockIdx.x >> 5;
    const int b = g >> 3, h = g & 7;
    const int i0 = rt * 16;

    const unsigned short* qg = qm + (size_t)g * 65536;
    const unsigned short* kg = km + (size_t)g * 65536;
    const unsigned short* vg = vm + (size_t)g * 65536;

    *(int4*)&mk[t * 4] = *(const int4*)(mask + b * 1024 + t * 4);

    const float pw0 = pw[b * 3 + 0], pw1 = pw[b * 3 + 1], pw2 = pw[b * 3 + 2];
    const bool a00 = pw1 > 0.05f;
    const bool a10 = (pw0 * 1.0f + pw1) > 0.05f;
    const bool a01 = (pw1 + pw2) > 0.05f;
    const bool a11 = ((pw0 * 1.0f + pw1) + pw2) > 0.05f;
    const bool need_sparse = (!a00 && a01) || (!a10 && a11);
    const bool flat_ok = (!need_sparse) && a00 && a10;  // allowed==true iff mk!=0, exactly
    const float w_h = sw[h], b_h = sb[h];
    __syncthreads();

    // ---- rare path: exact per-row kth (k=716), bitwise radix select ----
    unsigned kth_r[4] = {0u, 0u, 0u, 0u};
    if (need_sparse) {
        unsigned* ub = (unsigned*)&PO[w][0][0];
        for (int r = 0; r < 16; ++r) {
            for (int c = 0; c < 16; ++c) {
                const int col = c * 64 + l64;
                float s = 0.f;
                for (int e = 0; e < 64; ++e)
                    s += bf2f(qg[FRAGQK(i0 + r, e)]) * bf2f(kg[FRAGQK(col, e)]);
                unsigned uu = __float_as_uint(s * w_h + b_h);
                ub[col] = (uu & 0x80000000u) ? ~uu : (uu | 0x80000000u);
            }
            unsigned u[16];
            #pragma unroll
            for (int c = 0; c < 16; ++c) u[c] = ub[l64 + c * 64];
            unsigned act = 0xFFFFu, p = 0u;
            int kk = 716;
            for (int bit = 31; bit >= 0; --bit) {
                unsigned ones = 0u;
                #pragma unroll
                for (int c = 0; c < 16; ++c)
                    if (((act >> c) & 1u) && ((u[c] >> bit) & 1u)) ones |= (1u << c);
                int c1 = __popc(ones);
                for (int off = 32; off; off >>= 1) c1 += __shfl_xor(c1, off);
                if (kk <= c1) { p |= (1u << bit); act &= ones; }
                else          { kk -= c1; act &= ~ones; }
            }
            if (l64 == 0) kths[w][r] = p;
        }
        #pragma unroll
        for (int reg = 0; reg < 4; ++reg) kth_r[reg] = kths[w][quad * 4 + reg];
    }

    // ---- Q A-fragments (rows i0..i0+15): two contiguous 1KB blocks ----
    const short8 aq0 = *(const short8*)(qg + ((size_t)(i0 >> 4)) * 1024 + l64 * 8);
    const short8 aq1 = *(const short8*)(qg + ((size_t)(i0 >> 4)) * 1024 + 512 + l64 * 8);

    float m_r[4] = {-3e38f, -3e38f, -3e38f, -3e38f};
    float l_r[4] = {0.f, 0.f, 0.f, 0.f};
    floatx4 accv[4];
    #pragma unroll
    for (int et = 0; et < 4; ++et) accv[et] = (floatx4){0.f, 0.f, 0.f, 0.f};
    unsigned short* Pw = (unsigned short*)&PO[w][0][0];   // stride 136 shorts

    #pragma unroll
    for (int cc = 0; cc < 2; ++cc) {
        const int j0 = (w * 2 + cc) << 7;
        const bool mall = __all((mk[j0 + l64] != 0) && (mk[j0 + 64 + l64] != 0));
        const bool fast = flat_ok && mall;

        // ---- batch K-fragment loads: 16 contiguous 1KB wave loads ----
        const unsigned short* kbase = kg + ((size_t)(j0 >> 4)) * 1024 + l64 * 8;
        short8 kb0[8], kb1[8];
        #pragma unroll
        for (int nt = 0; nt < 8; ++nt) {
            kb0[nt] = *(const short8*)(kbase + nt * 1024);
            kb1[nt] = *(const short8*)(kbase + nt * 1024 + 512);
        }
        // V prefetch for et=0
        const unsigned short* vbase = vg + ((size_t)(j0 >> 7)) * 8192 + l64 * 8;
        short8 vb_cur[4], vb_nxt[4];
        #pragma unroll
        for (int ks = 0; ks < 4; ++ks)
            vb_cur[ks] = *(const short8*)(vbase + ks * 512);

        // ---- QK^T: 16 rows x 128 keys ----
        floatx4 sfr[8];
        #pragma unroll
        for (int nt = 0; nt < 8; ++nt) {
            floatx4 z = (floatx4){0.f, 0.f, 0.f, 0.f};
            z = MFMA16(aq0, kb0[nt], z);
            z = MFMA16(aq1, kb1[nt], z);
            sfr[nt] = z;
        }

        // ---- masking + row max ----
        float rm[4] = {-3e38f, -3e38f, -3e38f, -3e38f};
        if (fast) {
            #pragma unroll
            for (int nt = 0; nt < 8; ++nt)
                #pragma unroll
                for (int reg = 0; reg < 4; ++reg) rm[reg] = fmaxf(rm[reg], sfr[nt][reg]);
        } else {
            #pragma unroll
            for (int nt = 0; nt < 8; ++nt) {
                const int j = j0 + nt * 16 + ln;
                const bool mk0 = (mk[j] == 0);
                #pragma unroll
                for (int reg = 0; reg < 4; ++reg) {
                    const int i = i0 + quad * 4 + reg;
                    const float s = sfr[nt][reg];
                    const bool loc = (j >= i - 16) && (j <= i + 16);
                    bool sm = false;
                    if (need_sparse) {
                        unsigned uu = __float_as_uint(s * w_h + b_h);
                        unsigned key = (uu & 0x80000000u) ? ~uu : (uu | 0x80000000u);
                        sm = key >= kth_r[reg];
                    }
                    bool allowed = loc ? (sm ? a11 : a10) : (sm ? a01 : a00);
                    if (mk0) allowed = false;
                    const float se = allowed ? s : -1e9f;
                    sfr[nt][reg] = se;
                    rm[reg] = fmaxf(rm[reg], se);
                }
            }
        }
        #pragma unroll
        for (int reg = 0; reg < 4; ++reg) {
            float v = rm[reg];
            v = fmaxf(v, __shfl_xor(v, 1));
            v = fmaxf(v, __shfl_xor(v, 2));
            v = fmaxf(v, __shfl_xor(v, 4));
            v = fmaxf(v, __shfl_xor(v, 8));
            rm[reg] = v;
        }
        float alpha[4], rs[4];
        #pragma unroll
        for (int reg = 0; reg < 4; ++reg) {
            const float mn = fmaxf(m_r[reg], rm[reg]);
            alpha[reg] = __expf(m_r[reg] - mn);
            m_r[reg] = mn;
            rs[reg] = 0.f;
        }
        // ---- P = exp(s-m) -> bf16 -> wave-private LDS (C->A transpose) ----
        #pragma unroll
        for (int nt = 0; nt < 8; ++nt)
            #pragma unroll
            for (int reg = 0; reg < 4; ++reg) {
                const float p = __expf(sfr[nt][reg] - m_r[reg]);
                rs[reg] += p;
                Pw[(quad * 4 + reg) * 136 + nt * 16 + ln] = f2bf(p);
            }
        #pragma unroll
        for (int reg = 0; reg < 4; ++reg) {
            float v = rs[reg];
            v += __shfl_xor(v, 1);
            v += __shfl_xor(v, 2);
            v += __shfl_xor(v, 4);
            v += __shfl_xor(v, 8);
            l_r[reg] = l_r[reg] * alpha[reg] + v;
        }
        short8 pa[4];
        #pragma unroll
        for (int ks = 0; ks < 4; ++ks)
            pa[ks] = *(const short8*)&Pw[ln * 136 + ks * 32 + quad * 8];
        // ---- PV with et-pipelined V fragment loads ----
        #pragma unroll
        for (int et = 0; et < 4; ++et) {
            if (et < 3) {
                #pragma unroll
                for (int ks = 0; ks < 4; ++ks)
                    vb_nxt[ks] = *(const short8*)(vbase + ((et + 1) * 4 + ks) * 512);
            }
            floatx4 a = accv[et];
            a[0] *= alpha[0]; a[1] *= alpha[1]; a[2] *= alpha[2]; a[3] *= alpha[3];
            #pragma unroll
            for (int ks = 0; ks < 4; ++ks) a = MFMA16(pa[ks], vb_cur[ks], a);
            accv[et] = a;
            #pragma unroll
            for (int ks = 0; ks < 4; ++ks) vb_cur[ks] = vb_nxt[ks];
        }
    }

    // ---- per-wave partials into the (now-free) P region ----
    #pragma unroll
    for (int et = 0; et < 4; ++et)
        #pragma unroll
        for (int reg = 0; reg < 4; ++reg)
            PO[w][quad * 4 + reg][et * 16 + ln] = accv[et][reg];
    if (ln == 0) {
        #pragma unroll
        for (int reg = 0; reg < 4; ++reg) {
            msh[w][quad * 4 + reg] = m_r[reg];
            lsh[w][quad * 4 + reg] = l_r[reg];
        }
    }
    __syncthreads();

    // ---- merge 4 wave-partials -> output in fragment-order attnb ----
    {
        const int r = t >> 4, cb = (t & 15) * 4;
        float M = fmaxf(fmaxf(msh[0][r], msh[1][r]), fmaxf(msh[2][r], msh[3][r]));
        float L = 0.f;
        float4 o = make_float4(0.f, 0.f, 0.f, 0.f);
        #pragma unroll
        for (int wv = 0; wv < 4; ++wv) {
            const float sc = __expf(msh[wv][r] - M);
            L += lsh[wv][r] * sc;
            float4 ov = *(const float4*)&PO[wv][r][cb];
            o.x += ov.x * sc; o.y += ov.y * sc; o.z += ov.z * sc; o.w += ov.w * sc;
        }
        ushort4 res;
        if (M <= -1e9f + 1e-6f) {
            // v[0][e]: chunk 0, key 0 -> FRAGV(0, e) = (e>>4)*2048 + (e&15)*8
            res.x = vg[((cb + 0) >> 4) * 2048 + ((cb + 0) & 15) * 8];
            res.y = vg[((cb + 1) >> 4) * 2048 + ((cb + 1) & 15) * 8];
            res.z = vg[((cb + 2) >> 4) * 2048 + ((cb + 2) & 15) * 8];
            res.w = vg[((cb + 3) >> 4) * 2048 + ((cb + 3) & 15) * 8];
        } else {
            const float inv = 1.f / L;
            res.x = f2bf(o.x * inv); res.y = f2bf(o.y * inv);
            res.z = f2bf(o.z * inv); res.w = f2bf(o.w * inv);
        }
        const int row_g = b * 1024 + i0 + r;
        const int col = h * 64 + cb;
        *(ushort4*)&aout[FRAG512(row_g, col)] = res;
    }
}

// ============================================================
extern "C" void kernel_launch(void* const* d_in, const int* in_sizes, int n_in,
                              void* d_out, int out_size, void* d_ws, size_t ws_size,
                              hipStream_t stream) {
    const float* x     = (const float*)d_in[0];
    const int*   mask  = (const int*)d_in[1];
    const float* Wqkv  = (const float*)d_in[2];
    const float* Wproj = (const float*)d_in[3];
    const float* bproj = (const float*)d_in[4];
    const float* Wsel1 = (const float*)d_in[5];
    const float* bsel1 = (const float*)d_in[6];
    const float* Wsel2 = (const float*)d_in[7];
    const float* bsel2 = (const float*)d_in[8];
    const float* ltau  = (const float*)d_in[9];
    const float* sw    = (const float*)d_in[10];
    const float* sb    = (const float*)d_in[11];
    char* ws = (char*)d_ws;
    unsigned short* xb     = (unsigned short*)(ws + OFF_XB);
    unsigned short* wqkvb  = (unsigned short*)(ws + OFF_WQKV);
    unsigned short* wprojb = (unsigned short*)(ws + OFF_WPROJ);
    unsigned short* q      = (unsigned short*)(ws + OFF_Q);
    unsigned short* k      = (unsigned short*)(ws + OFF_K);
    unsigned short* v      = (unsigned short*)(ws + OFF_VT);
    unsigned short* attnb  = (unsigned short*)(ws + OFF_AT);
    float* pw  = (float*)(ws + OFF_PW);
    float* par = (float*)(ws + OFF_PAR);
    float* out = (float*)d_out;
    (void)in_sizes; (void)n_in; (void)out_size; (void)ws_size;

    cvt_all<<<640, 256, 0, stream>>>(x, Wqkv, Wproj, xb, wqkvb, wprojb, par);
    selector_kernel<<<4, 256, 0, stream>>>(par, Wsel1, bsel1, Wsel2, bsel2, ltau, pw);
    gemm_qkv<<<dim3(12, 32), 256, 0, stream>>>(xb, wqkvb, q, k, v);
    attn_mfma<<<2048, 256, 0, stream>>>(q, k, v, mask, pw, sw, sb, attnb);
    gemm_proj<<<dim3(8, 32), 256, 0, stream>>>(attnb, wprojb, bproj, out);
}

// Round 7
// 158.935 us; speedup vs baseline: 4.3907x; 1.0308x over previous
//
#include <hip/hip_runtime.h>
#include <math.h>

typedef __attribute__((ext_vector_type(8))) short short8;
typedef __attribute__((ext_vector_type(4))) float floatx4;

#define MFMA16(a, b, c) __builtin_amdgcn_mfma_f32_16x16x32_bf16(a, b, c, 0, 0, 0)

// ---- fixed sizes: B=4 L=1024 D=512 H=8 HD=64 HID=256 half-win=16 KK=716 scale=1/8 ----
//
// FRAGMENT-ORDER LAYOUTS: every staged tensor stored as 512-short (1KB) MFMA
// fragment blocks; lane l64's 8 shorts at base + l64*8. All fragment loads are
// contiguous 1KB wave loads (full-line coalesced).

#define FRAG512(row, k) (((size_t)((row) >> 4)) * 8192 + (((k) >> 5) * 512) + \
                         ((((k) >> 3) & 3) * 128) + (((row) & 15) * 8) + ((k) & 7))
#define FRAGQK(row, e)  (((size_t)((row) >> 4)) * 1024 + (((e) >> 5) * 512) + \
                         ((((e) >> 3) & 3) * 128) + (((row) & 15) * 8) + ((e) & 7))

// ---- workspace byte offsets ----
#define OFF_XB    ((size_t)0)          // x bf16 frag [4096][512]
#define OFF_WQKV  ((size_t)4194304)    // Wqkv bf16 frag [1536][512]
#define OFF_WPROJ ((size_t)5767168)    // Wproj bf16 frag [512][512]
#define OFF_Q     ((size_t)6291456)    // q bf16 frag [32][1024][64] (scale folded)
#define OFF_K     ((size_t)10485760)   // k bf16 frag [32][1024][64]
#define OFF_VT    ((size_t)14680064)   // v bf16 frag [32] chunks
#define OFF_AT    ((size_t)18874368)   // attn out bf16 frag [4096][512]
#define OFF_PW    ((size_t)23068672)   // pw fp32 [4][3]
#define OFF_PAR   ((size_t)23069696)   // pool partials fp32 [4][64][512]

__device__ __forceinline__ unsigned short f2bf(float f) {  // RNE
    unsigned u = __float_as_uint(f);
    return (unsigned short)((u + 0x7fffu + ((u >> 16) & 1u)) >> 16);
}
__device__ __forceinline__ float bf2f(unsigned short s) {
    return __uint_as_float((unsigned)s << 16);
}

// ============================================================
// fp32 [16][512] row-major tile -> bf16 fragment-order tile (8192 shorts).
// ============================================================
__device__ __forceinline__ void frag_cvt_tile(const float* __restrict__ src,
                                              unsigned short* __restrict__ dst,
                                              const int t, const float sc)
{
    const int ln = t & 15, quad = (t >> 4) & 3, kh = t >> 6;
    #pragma unroll
    for (int i = 0; i < 4; ++i) {
        const int kb = kh + i * 4;                 // 0..15
        const float* s = src + (size_t)ln * 512 + kb * 32 + quad * 8;
        float4 f0 = *(const float4*)s;
        float4 f1 = *(const float4*)(s + 4);
        unsigned short o[8] = { f2bf(f0.x * sc), f2bf(f0.y * sc), f2bf(f0.z * sc), f2bf(f0.w * sc),
                                f2bf(f1.x * sc), f2bf(f1.y * sc), f2bf(f1.z * sc), f2bf(f1.w * sc) };
        unsigned short* d = dst + kb * 512 + (size_t)(t & 63) * 8;
        *(ushort4*)d       = make_ushort4(o[0], o[1], o[2], o[3]);
        *(ushort4*)(d + 4) = make_ushort4(o[4], o[5], o[6], o[7]);
    }
}

// ============================================================
// grid 640: [0,256) pooling partials; [256,512) x->frag; [512,640) weights->frag
// ============================================================
__global__ __launch_bounds__(256)
void cvt_all(const float* __restrict__ x, const float* __restrict__ wqkv,
             const float* __restrict__ wproj, unsigned short* __restrict__ xb,
             unsigned short* __restrict__ oq, unsigned short* __restrict__ op,
             float* __restrict__ partial)
{
    const int bid = blockIdx.x, t = threadIdx.x;
    if (bid < 256) {
        const int b = bid >> 6, lb = bid & 63;
        const size_t base = ((size_t)b * 1024 + lb * 16) * 512;
        float s0 = 0.f, s1 = 0.f;
        #pragma unroll 4
        for (int l = 0; l < 16; ++l) {
            s0 += x[base + (size_t)l * 512 + t];
            s1 += x[base + (size_t)l * 512 + t + 256];
        }
        partial[((size_t)b * 64 + lb) * 512 + t] = s0;
        partial[((size_t)b * 64 + lb) * 512 + t + 256] = s1;
    } else if (bid < 512) {
        const int rt = bid - 256;                  // 0..255
        frag_cvt_tile(x + (size_t)rt * 16 * 512, xb + (size_t)rt * 8192, t, 1.f);
    } else {
        const int tile = bid - 512;                // 0..127
        if (tile < 96)
            frag_cvt_tile(wqkv + (size_t)tile * 16 * 512, oq + (size_t)tile * 8192, t, 1.f);
        else
            frag_cvt_tile(wproj + (size_t)(tile - 96) * 16 * 512,
                          op + (size_t)(tile - 96) * 8192, t, 1.f);
    }
}

// ============================================================
// QKV GEMM + selector fold. block 128 (2 waves), grid (12, 65).
// by<64: barrier-free direct-global GEMM, tile 64m x 128n (wave tile 64x64),
//        register double-buffer, frag-order in AND out. Zero __syncthreads.
// by==64, bx<4: pattern-selector MLP for batch bx (hidden under the GEMM).
// ============================================================
__global__ __launch_bounds__(128)
void gemm_qkv_sel(const unsigned short* __restrict__ xb, const unsigned short* __restrict__ wb,
                  unsigned short* __restrict__ qo, unsigned short* __restrict__ ko,
                  unsigned short* __restrict__ vo,
                  const float* __restrict__ partial, const float* __restrict__ W1,
                  const float* __restrict__ b1, const float* __restrict__ W2,
                  const float* __restrict__ b2, const float* __restrict__ ltau,
                  float* __restrict__ pwout)
{
    __shared__ __align__(16) unsigned short tile[2][64 * 72];   // per-wave epilogue / selector scratch
    const int bx = blockIdx.x, by = blockIdx.y;
    const int t = threadIdx.x;

    if (by == 64) {
        if (bx >= 4) return;
        // ---- selector (b = bx), 128 threads ----
        float* pooled = (float*)&tile[0][0];   // 512 f
        float* h1 = pooled + 512;              // 256 f
        float* lg = h1 + 256;                  // 3 f
        const int b = bx;
        #pragma unroll
        for (int c = 0; c < 4; ++c) {
            const int col = t + c * 128;
            float s = 0.f;
            for (int p = 0; p < 64; ++p) s += partial[((size_t)b * 64 + p) * 512 + col];
            pooled[col] = s * (1.f / 1024.f);
        }
        __syncthreads();
        for (int r = t; r < 256; r += 128) {
            float acc = b1[r];
            const float* w1 = W1 + (size_t)r * 512;
            for (int d = 0; d < 512; d += 4) {
                float4 w4 = *(const float4*)(w1 + d);
                acc += w4.x * pooled[d] + w4.y * pooled[d + 1] +
                       w4.z * pooled[d + 2] + w4.w * pooled[d + 3];
            }
            h1[r] = fmaxf(acc, 0.f);
        }
        __syncthreads();
        if (t < 3) {
            float a = b2[t];
            const float* w2 = W2 + t * 256;
            for (int i = 0; i < 256; ++i) a += w2[i] * h1[i];
            float tauv = fminf(fmaxf(expf(ltau[0]), 1e-4f), 10.f);
            lg[t] = a / tauv;
        }
        __syncthreads();
        if (t == 0) {
            float m = fmaxf(lg[0], fmaxf(lg[1], lg[2]));
            float e0 = expf(lg[0] - m), e1 = expf(lg[1] - m), e2 = expf(lg[2] - m);
            float inv = 1.f / (e0 + e1 + e2);
            pwout[b * 3 + 0] = e0 * inv;
            pwout[b * 3 + 1] = e1 * inv;
            pwout[b * 3 + 2] = e2 * inv;
        }
        return;
    }

    // ---- GEMM path ----
    const int w = t >> 6, l64 = t & 63;
    const int ln = l64 & 15, quad = l64 >> 4;
    const int m0 = by << 6;
    const int nb0 = (bx << 7) + (w << 6);       // this wave's 64-col range (one head)

    const unsigned short* Abase = xb + ((size_t)(m0 >> 4)) * 8192 + l64 * 8;
    const unsigned short* Bbase = wb + ((size_t)(nb0 >> 4)) * 8192 + l64 * 8;

    floatx4 acc[4][4];
    #pragma unroll
    for (int i = 0; i < 4; ++i)
        #pragma unroll
        for (int j = 0; j < 4; ++j) acc[i][j] = (floatx4){0.f, 0.f, 0.f, 0.f};

    short8 a0[4], b0[4], a1[4], b1v[4];
    #pragma unroll
    for (int i = 0; i < 4; ++i) {
        a0[i] = *(const short8*)(Abase + (size_t)i * 8192);
        b0[i] = *(const short8*)(Bbase + (size_t)i * 8192);
    }
    for (int s = 0; s < 16; s += 2) {
        #pragma unroll
        for (int i = 0; i < 4; ++i) {
            a1v: ;
            a1[i]  = *(const short8*)(Abase + (size_t)i * 8192 + (s + 1) * 512);
            b1v[i] = *(const short8*)(Bbase + (size_t)i * 8192 + (s + 1) * 512);
        }
        #pragma unroll
        for (int i = 0; i < 4; ++i)
            #pragma unroll
            for (int j = 0; j < 4; ++j)
                acc[i][j] = MFMA16(a0[i], b0[j], acc[i][j]);
        if (s + 2 < 16) {
            #pragma unroll
            for (int i = 0; i < 4; ++i) {
                a0[i] = *(const short8*)(Abase + (size_t)i * 8192 + (s + 2) * 512);
                b0[i] = *(const short8*)(Bbase + (size_t)i * 8192 + (s + 2) * 512);
            }
        }
        #pragma unroll
        for (int i = 0; i < 4; ++i)
            #pragma unroll
            for (int j = 0; j < 4; ++j)
                acc[i][j] = MFMA16(a1[i], b1v[j], acc[i][j]);
    }

    // ---- epilogue: wave-private 64x72 LDS transpose -> fragment-order stores ----
    unsigned short* tw = &tile[w][0];
    const int which = bx >> 2;                    // 0=q 1=k 2=v
    const int hh = (nb0 >> 6) & 7;
    const int g = (by >> 4) * 8 + hh;
    const int lrow0 = m0 & 1023;                  // 64-row range within batch

    if (which == 2) {
        // tile[e][key_local]
        #pragma unroll
        for (int j = 0; j < 4; ++j)
            #pragma unroll
            for (int i = 0; i < 4; ++i)
                #pragma unroll
                for (int reg = 0; reg < 4; ++reg)
                    tw[(j * 16 + ln) * 72 + i * 16 + quad * 4 + reg] = f2bf(acc[i][j][reg]);
        const int chunk = lrow0 >> 7;
        const int ks0 = (lrow0 & 127) >> 5;       // 0 or 2
        unsigned short* dst = vo + (size_t)g * 65536 + (size_t)chunk * 8192;
        #pragma unroll
        for (int et = 0; et < 4; ++et)
            #pragma unroll
            for (int ksl = 0; ksl < 2; ++ksl) {
                const unsigned short* srcp = &tw[(et * 16 + ln) * 72 + ksl * 32 + quad * 8];
                *(short8*)(dst + (et * 4 + ks0 + ksl) * 512 + l64 * 8) = *(const short8*)srcp;
            }
    } else {
        const float sc = (which == 0) ? 0.125f : 1.f;   // fold q scale (pow2, exact)
        // tile[row_local][e]
        #pragma unroll
        for (int j = 0; j < 4; ++j)
            #pragma unroll
            for (int i = 0; i < 4; ++i)
                #pragma unroll
                for (int reg = 0; reg < 4; ++reg)
                    tw[(i * 16 + quad * 4 + reg) * 72 + j * 16 + ln] = f2bf(acc[i][j][reg] * sc);
        unsigned short* dst = (which == 0 ? qo : ko) + (size_t)g * 65536;
        #pragma unroll
        for (int rt = 0; rt < 4; ++rt)
            #pragma unroll
            for (int eh = 0; eh < 2; ++eh) {
                const unsigned short* srcp = &tw[(rt * 16 + ln) * 72 + eh * 32 + quad * 8];
                *(short8*)(dst + ((size_t)((lrow0 >> 4) + rt)) * 1024 + eh * 512 + l64 * 8) =
                    *(const short8*)srcp;
            }
    }
}

// ============================================================
// Proj GEMM: barrier-free direct-global, 64x64 tile per 1-wave block.
// grid (8, 64) = 512 blocks. fp32 out + bias, row-major stores.
// ============================================================
__global__ __launch_bounds__(64)
void gemm_proj(const unsigned short* __restrict__ ab, const unsigned short* __restrict__ wb,
               const float* __restrict__ bias, float* __restrict__ out)
{
    const int t = threadIdx.x;                    // 0..63
    const int ln = t & 15, quad = t >> 4;
    const int n0 = blockIdx.x << 6, m0 = blockIdx.y << 6;

    const unsigned short* Abase = ab + ((size_t)(m0 >> 4)) * 8192 + t * 8;
    const unsigned short* Bbase = wb + ((size_t)(n0 >> 4)) * 8192 + t * 8;

    floatx4 acc[4][4];
    #pragma unroll
    for (int i = 0; i < 4; ++i)
        #pragma unroll
        for (int j = 0; j < 4; ++j) acc[i][j] = (floatx4){0.f, 0.f, 0.f, 0.f};

    short8 a0[4], b0[4], a1[4], b1v[4];
    #pragma unroll
    for (int i = 0; i < 4; ++i) {
        a0[i] = *(const short8*)(Abase + (size_t)i * 8192);
        b0[i] = *(const short8*)(Bbase + (size_t)i * 8192);
    }
    for (int s = 0; s < 16; s += 2) {
        #pragma unroll
        for (int i = 0; i < 4; ++i) {
            a1[i]  = *(const short8*)(Abase + (size_t)i * 8192 + (s + 1) * 512);
            b1v[i] = *(const short8*)(Bbase + (size_t)i * 8192 + (s + 1) * 512);
        }
        #pragma unroll
        for (int i = 0; i < 4; ++i)
            #pragma unroll
            for (int j = 0; j < 4; ++j)
                acc[i][j] = MFMA16(a0[i], b0[j], acc[i][j]);
        if (s + 2 < 16) {
            #pragma unroll
            for (int i = 0; i < 4; ++i) {
                a0[i] = *(const short8*)(Abase + (size_t)i * 8192 + (s + 2) * 512);
                b0[i] = *(const short8*)(Bbase + (size_t)i * 8192 + (s + 2) * 512);
            }
        }
        #pragma unroll
        for (int i = 0; i < 4; ++i)
            #pragma unroll
            for (int j = 0; j < 4; ++j)
                acc[i][j] = MFMA16(a1[i], b1v[j], acc[i][j]);
    }
    #pragma unroll
    for (int j = 0; j < 4; ++j) {
        const float bv = bias[n0 + j * 16 + ln];
        #pragma unroll
        for (int i = 0; i < 4; ++i)
            #pragma unroll
            for (int reg = 0; reg < 4; ++reg)
                out[(size_t)(m0 + i * 16 + quad * 4 + reg) * 512 + n0 + j * 16 + ln] =
                    acc[i][j][reg] + bv;
    }
}

// ============================================================
// Fused attention (unchanged from round 6 — kept identical for attribution).
// ============================================================
__global__ __launch_bounds__(256)
void attn_mfma(const unsigned short* __restrict__ qm, const unsigned short* __restrict__ km,
               const unsigned short* __restrict__ vm, const int* __restrict__ mask,
               const float* __restrict__ pw, const float* __restrict__ sw,
               const float* __restrict__ sb, unsigned short* __restrict__ aout)
{
    __shared__ int mk[1024];
    __shared__ float PO[4][16][68];   // per-wave union: P bf16[16][136] / radix ubuf / Opart
    __shared__ float msh[4][16], lsh[4][16];
    __shared__ unsigned kths[4][16];

    const int t = threadIdx.x;
    const int w = t >> 6, l64 = t & 63;
    const int ln = l64 & 15, quad = l64 >> 4;
    const int g = blockIdx.x & 31;
    const int rt = blockIdx.x >> 5;
    const int b = g >> 3, h = g & 7;
    const int i0 = rt * 16;

    const unsigned short* qg = qm + (size_t)g * 65536;
    const unsigned short* kg = km + (size_t)g * 65536;
    const unsigned short* vg = vm + (size_t)g * 65536;

    *(int4*)&mk[t * 4] = *(const int4*)(mask + b * 1024 + t * 4);

    const float pw0 = pw[b * 3 + 0], pw1 = pw[b * 3 + 1], pw2 = pw[b * 3 + 2];
    const bool a00 = pw1 > 0.05f;
    const bool a10 = (pw0 * 1.0f + pw1) > 0.05f;
    const bool a01 = (pw1 + pw2) > 0.05f;
    const bool a11 = ((pw0 * 1.0f + pw1) + pw2) > 0.05f;
    const bool need_sparse = (!a00 && a01) || (!a10 && a11);
    const bool flat_ok = (!need_sparse) && a00 && a10;  // allowed==true iff mk!=0, exactly
    const float w_h = sw[h], b_h = sb[h];
    __syncthreads();

    // ---- rare path: exact per-row kth (k=716), bitwise radix select ----
    unsigned kth_r[4] = {0u, 0u, 0u, 0u};
    if (need_sparse) {
        unsigned* ub = (unsigned*)&PO[w][0][0];
        for (int r = 0; r < 16; ++r) {
            for (int c = 0; c < 16; ++c) {
                const int col = c * 64 + l64;
                float s = 0.f;
                for (int e = 0; e < 64; ++e)
                    s += bf2f(qg[FRAGQK(i0 + r, e)]) * bf2f(kg[FRAGQK(col, e)]);
                unsigned uu = __float_as_uint(s * w_h + b_h);
                ub[col] = (uu & 0x80000000u) ? ~uu : (uu | 0x80000000u);
            }
            unsigned u[16];
            #pragma unroll
            for (int c = 0; c < 16; ++c) u[c] = ub[l64 + c * 64];
            unsigned act = 0xFFFFu, p = 0u;
            int kk = 716;
            for (int bit = 31; bit >= 0; --bit) {
                unsigned ones = 0u;
                #pragma unroll
                for (int c = 0; c < 16; ++c)
                    if (((act >> c) & 1u) && ((u[c] >> bit) & 1u)) ones |= (1u << c);
                int c1 = __popc(ones);
                for (int off = 32; off; off >>= 1) c1 += __shfl_xor(c1, off);
                if (kk <= c1) { p |= (1u << bit); act &= ones; }
                else          { kk -= c1; act &= ~ones; }
            }
            if (l64 == 0) kths[w][r] = p;
        }
        #pragma unroll
        for (int reg = 0; reg < 4; ++reg) kth_r[reg] = kths[w][quad * 4 + reg];
    }

    // ---- Q A-fragments (rows i0..i0+15): two contiguous 1KB blocks ----
    const short8 aq0 = *(const short8*)(qg + ((size_t)(i0 >> 4)) * 1024 + l64 * 8);
    const short8 aq1 = *(const short8*)(qg + ((size_t)(i0 >> 4)) * 1024 + 512 + l64 * 8);

    float m_r[4] = {-3e38f, -3e38f, -3e38f, -3e38f};
    float l_r[4] = {0.f, 0.f, 0.f, 0.f};
    floatx4 accv[4];
    #pragma unroll
    for (int et = 0; et < 4; ++et) accv[et] = (floatx4){0.f, 0.f, 0.f, 0.f};
    unsigned short* Pw = (unsigned short*)&PO[w][0][0];   // stride 136 shorts

    #pragma unroll
    for (int cc = 0; cc < 2; ++cc) {
        const int j0 = (w * 2 + cc) << 7;
        const bool mall = __all((mk[j0 + l64] != 0) && (mk[j0 + 64 + l64] != 0));
        const bool fast = flat_ok && mall;

        // ---- batch K-fragment loads: 16 contiguous 1KB wave loads ----
        const unsigned short* kbase = kg + ((size_t)(j0 >> 4)) * 1024 + l64 * 8;
        short8 kb0[8], kb1[8];
        #pragma unroll
        for (int nt = 0; nt < 8; ++nt) {
            kb0[nt] = *(const short8*)(kbase + nt * 1024);
            kb1[nt] = *(const short8*)(kbase + nt * 1024 + 512);
        }
        // V prefetch for et=0
        const unsigned short* vbase = vg + ((size_t)(j0 >> 7)) * 8192 + l64 * 8;
        short8 vb_cur[4], vb_nxt[4];
        #pragma unroll
        for (int ks = 0; ks < 4; ++ks)
            vb_cur[ks] = *(const short8*)(vbase + ks * 512);

        // ---- QK^T: 16 rows x 128 keys ----
        floatx4 sfr[8];
        #pragma unroll
        for (int nt = 0; nt < 8; ++nt) {
            floatx4 z = (floatx4){0.f, 0.f, 0.f, 0.f};
            z = MFMA16(aq0, kb0[nt], z);
            z = MFMA16(aq1, kb1[nt], z);
            sfr[nt] = z;
        }

        // ---- masking + row max ----
        float rm[4] = {-3e38f, -3e38f, -3e38f, -3e38f};
        if (fast) {
            #pragma unroll
            for (int nt = 0; nt < 8; ++nt)
                #pragma unroll
                for (int reg = 0; reg < 4; ++reg) rm[reg] = fmaxf(rm[reg], sfr[nt][reg]);
        } else {
            #pragma unroll
            for (int nt = 0; nt < 8; ++nt) {
                const int j = j0 + nt * 16 + ln;
                const bool mk0 = (mk[j] == 0);
                #pragma unroll
                for (int reg = 0; reg < 4; ++reg) {
                    const int i = i0 + quad * 4 + reg;
                    const float s = sfr[nt][reg];
                    const bool loc = (j >= i - 16) && (j <= i + 16);
                    bool sm = false;
                    if (need_sparse) {
                        unsigned uu = __float_as_uint(s * w_h + b_h);
                        unsigned key = (uu & 0x80000000u) ? ~uu : (uu | 0x80000000u);
                        sm = key >= kth_r[reg];
                    }
                    bool allowed = loc ? (sm ? a11 : a10) : (sm ? a01 : a00);
                    if (mk0) allowed = false;
                    const float se = allowed ? s : -1e9f;
                    sfr[nt][reg] = se;
                    rm[reg] = fmaxf(rm[reg], se);
                }
            }
        }
        #pragma unroll
        for (int reg = 0; reg < 4; ++reg) {
            float v = rm[reg];
            v = fmaxf(v, __shfl_xor(v, 1));
            v = fmaxf(v, __shfl_xor(v, 2));
            v = fmaxf(v, __shfl_xor(v, 4));
            v = fmaxf(v, __shfl_xor(v, 8));
            rm[reg] = v;
        }
        float alpha[4], rs[4];
        #pragma unroll
        for (int reg = 0; reg < 4; ++reg) {
            const float mn = fmaxf(m_r[reg], rm[reg]);
            alpha[reg] = __expf(m_r[reg] - mn);
            m_r[reg] = mn;
            rs[reg] = 0.f;
        }
        // ---- P = exp(s-m) -> bf16 -> wave-private LDS (C->A transpose) ----
        #pragma unroll
        for (int nt = 0; nt < 8; ++nt)
            #pragma unroll
            for (int reg = 0; reg < 4; ++reg) {
                const float p = __expf(sfr[nt][reg] - m_r[reg]);
                rs[reg] += p;
                Pw[(quad * 4 + reg) * 136 + nt * 16 + ln] = f2bf(p);
            }
        #pragma unroll
        for (int reg = 0; reg < 4; ++reg) {
            float v = rs[reg];
            v += __shfl_xor(v, 1);
            v += __shfl_xor(v, 2);
            v += __shfl_xor(v, 4);
            v += __shfl_xor(v, 8);
            l_r[reg] = l_r[reg] * alpha[reg] + v;
        }
        short8 pa[4];
        #pragma unroll
        for (int ks = 0; ks < 4; ++ks)
            pa[ks] = *(const short8*)&Pw[ln * 136 + ks * 32 + quad * 8];
        // ---- PV with et-pipelined V fragment loads ----
        #pragma unroll
        for (int et = 0; et < 4; ++et) {
            if (et < 3) {
                #pragma unroll
                for (int ks = 0; ks < 4; ++ks)
                    vb_nxt[ks] = *(const short8*)(vbase + ((et + 1) * 4 + ks) * 512);
            }
            floatx4 a = accv[et];
            a[0] *= alpha[0]; a[1] *= alpha[1]; a[2] *= alpha[2]; a[3] *= alpha[3];
            #pragma unroll
            for (int ks = 0; ks < 4; ++ks) a = MFMA16(pa[ks], vb_cur[ks], a);
            accv[et] = a;
            #pragma unroll
            for (int ks = 0; ks < 4; ++ks) vb_cur[ks] = vb_nxt[ks];
        }
    }

    // ---- per-wave partials into the (now-free) P region ----
    #pragma unroll
    for (int et = 0; et < 4; ++et)
        #pragma unroll
        for (int reg = 0; reg < 4; ++reg)
            PO[w][quad * 4 + reg][et * 16 + ln] = accv[et][reg];
    if (ln == 0) {
        #pragma unroll
        for (int reg = 0; reg < 4; ++reg) {
            msh[w][quad * 4 + reg] = m_r[reg];
            lsh[w][quad * 4 + reg] = l_r[reg];
        }
    }
    __syncthreads();

    // ---- merge 4 wave-partials -> output in fragment-order attnb ----
    {
        const int r = t >> 4, cb = (t & 15) * 4;
        float M = fmaxf(fmaxf(msh[0][r], msh[1][r]), fmaxf(msh[2][r], msh[3][r]));
        float L = 0.f;
        float4 o = make_float4(0.f, 0.f, 0.f, 0.f);
        #pragma unroll
        for (int wv = 0; wv < 4; ++wv) {
            const float sc = __expf(msh[wv][r] - M);
            L += lsh[wv][r] * sc;
            float4 ov = *(const float4*)&PO[wv][r][cb];
            o.x += ov.x * sc; o.y += ov.y * sc; o.z += ov.z * sc; o.w += ov.w * sc;
        }
        ushort4 res;
        if (M <= -1e9f + 1e-6f) {
            // v[0][e]: chunk 0, key 0 -> FRAGV(0, e) = (e>>4)*2048 + (e&15)*8
            res.x = vg[((cb + 0) >> 4) * 2048 + ((cb + 0) & 15) * 8];
            res.y = vg[((cb + 1) >> 4) * 2048 + ((cb + 1) & 15) * 8];
            res.z = vg[((cb + 2) >> 4) * 2048 + ((cb + 2) & 15) * 8];
            res.w = vg[((cb + 3) >> 4) * 2048 + ((cb + 3) & 15) * 8];
        } else {
            const float inv = 1.f / L;
            res.x = f2bf(o.x * inv); res.y = f2bf(o.y * inv);
            res.z = f2bf(o.z * inv); res.w = f2bf(o.w * inv);
        }
        const int row_g = b * 1024 + i0 + r;
        const int col = h * 64 + cb;
        *(ushort4*)&aout[FRAG512(row_g, col)] = res;
    }
}

// ============================================================
extern "C" void kernel_launch(void* const* d_in, const int* in_sizes, int n_in,
                              void* d_out, int out_size, void* d_ws, size_t ws_size,
                              hipStream_t stream) {
    const float* x     = (const float*)d_in[0];
    const int*   mask  = (const int*)d_in[1];
    const float* Wqkv  = (const float*)d_in[2];
    const float* Wproj = (const float*)d_in[3];
    const float* bproj = (const float*)d_in[4];
    const float* Wsel1 = (const float*)d_in[5];
    const float* bsel1 = (const float*)d_in[6];
    const float* Wsel2 = (const float*)d_in[7];
    const float* bsel2 = (const float*)d_in[8];
    const float* ltau  = (const float*)d_in[9];
    const float* sw    = (const float*)d_in[10];
    const float* sb    = (const float*)d_in[11];
    char* ws = (char*)d_ws;
    unsigned short* xb     = (unsigned short*)(ws + OFF_XB);
    unsigned short* wqkvb  = (unsigned short*)(ws + OFF_WQKV);
    unsigned short* wprojb = (unsigned short*)(ws + OFF_WPROJ);
    unsigned short* q      = (unsigned short*)(ws + OFF_Q);
    unsigned short* k      = (unsigned short*)(ws + OFF_K);
    unsigned short* v      = (unsigned short*)(ws + OFF_VT);
    unsigned short* attnb  = (unsigned short*)(ws + OFF_AT);
    float* pw  = (float*)(ws + OFF_PW);
    float* par = (float*)(ws + OFF_PAR);
    float* out = (float*)d_out;
    (void)in_sizes; (void)n_in; (void)out_size; (void)ws_size;

    cvt_all<<<640, 256, 0, stream>>>(x, Wqkv, Wproj, xb, wqkvb, wprojb, par);
    gemm_qkv_sel<<<dim3(12, 65), 128, 0, stream>>>(xb, wqkvb, q, k, v,
                                                   par, Wsel1, bsel1, Wsel2, bsel2, ltau, pw);
    attn_mfma<<<2048, 256, 0, stream>>>(q, k, v, mask, pw, sw, sb, attnb);
    gemm_proj<<<dim3(8, 64), 64, 0, stream>>>(attnb, wprojb, bproj, out);
}